// Round 18
// baseline (288.673 us; speedup 1.0000x reference)
//
#include <hip/hip_runtime.h>
#include <hip/hip_bf16.h>
#include <math.h>

#define SCALE_L2E  0.22811011265722836f   // (1/sqrt(40)) * log2(e)

typedef __attribute__((ext_vector_type(8))) short short8v;
typedef __attribute__((ext_vector_type(4))) float float4v;
typedef unsigned short u16;

__device__ __forceinline__ unsigned pack2(float a, float b) {
  float2 f; f.x = a; f.y = b;
  __hip_bfloat162 h = __float22bfloat162_rn(f);
  return *(unsigned*)&h;
}
__device__ __forceinline__ float bfu2f(u16 u) {
  return __uint_as_float(((unsigned)u) << 16);
}
__device__ __forceinline__ u16 f2bf(float x) {
  __hip_bfloat16 h = __float2bfloat16(x);
  return *(u16*)&h;
}

// ---------------- prep: weight transpose+convert | ctx cvt | gn PARTIAL stats --------------
struct TDesc { const float* src; u16* dst; int K, N, off, tx; float sc; };
struct TPack { TDesc d[12]; };

__global__ __launch_bounds__(256) void prep_kernel(
    TPack p, int nT,
    const float* __restrict__ ctxsrc, u16* __restrict__ ctxdst,
    const float* __restrict__ x,
    float* __restrict__ psum, float* __restrict__ psq) {
  __shared__ float ls[32][33];
  int bt = blockIdx.x, t = threadIdx.x;
  if (bt < nT) {
    int ti = 0;
    #pragma unroll
    for (int i = 1; i < 12; i++) if (bt >= p.d[i].off) ti = i;
    TDesc dd = p.d[ti];
    int local = bt - dd.off;
    int n0 = (local % dd.tx) * 32, k0 = (local / dd.tx) * 32;
    #pragma unroll
    for (int i = 0; i < 4; i++) {
      int idx = t + i*256, r = idx >> 5, c = idx & 31;
      ls[r][c] = dd.src[(size_t)(k0 + r)*dd.N + n0 + c];
    }
    __syncthreads();
    #pragma unroll
    for (int i = 0; i < 2; i++) {
      int p2 = t + i*256, n = p2 >> 4, kp = (p2 & 15)*2;
      *(unsigned*)&dd.dst[(size_t)(n0 + n)*dd.K + k0 + kp] =
        pack2(ls[kp][n]*dd.sc, ls[kp+1][n]*dd.sc);
    }
  } else if (bt < nT + 58) {
    int idx = ((bt - nT)*256 + t)*4;
    if (idx < 59136) {
      float4 v = *(const float4*)&ctxsrc[idx];
      uint2 o; o.x = pack2(v.x, v.y); o.y = pack2(v.z, v.w);
      *(uint2*)&ctxdst[idx] = o;
    }
  } else {
    int pp = bt - nT - 58;            // 0..255
    int g = pp >> 3, part = pp & 7;
    size_t base = (size_t)g*40960 + (size_t)part*5120;
    float sum = 0.f, sq = 0.f;
    #pragma unroll
    for (int r = 0; r < 5; r++) {
      float4 v = *(const float4*)&x[base + (size_t)(t + r*256)*4];
      sum += v.x + v.y + v.z + v.w;
      sq  += v.x*v.x + v.y*v.y + v.z*v.z + v.w*v.w;
    }
    float* s1 = &ls[0][0];
    float* s2 = &ls[8][0] + 8;
    s1[t] = sum; s2[t] = sq; __syncthreads();
    for (int st = 128; st > 0; st >>= 1) {
      if (t < st) { s1[t] += s1[t+st]; s2[t] += s2[t+st]; }
      __syncthreads();
    }
    if (t == 0) { psum[pp] = s1[0]; psq[pp] = s2[0]; }
  }
}

// ---------------- fused: GN apply+transpose (blocks 0..319) | kc/vc GEMM (320..339) --------
__global__ __launch_bounds__(256) void gn_kcvc(
    const float* __restrict__ x, const float* __restrict__ psum,
    const float* __restrict__ psq, const float* __restrict__ gs,
    const float* __restrict__ gb, u16* __restrict__ gnT,
    const u16* __restrict__ ctxb, const u16* __restrict__ wk2T,
    u16* __restrict__ kcvc) {
  __shared__ __align__(16) u16 smem[2*64*72];
  __shared__ float scl[64], sft[64];
  const int t = threadIdx.x;
  if (blockIdx.x < 320) {
    float* ts = (float*)smem;
    int s0 = (blockIdx.x & 63) * 64, c0 = (blockIdx.x >> 6) * 64;
    if (t < 64) {
      int c = c0 + t, g = c / 10;
      float s = 0.f, q = 0.f;
      #pragma unroll
      for (int i = 0; i < 8; i++) { s += psum[g*8 + i]; q += psq[g*8 + i]; }
      float mu = s * (1.f/40960.f);
      float var = q * (1.f/40960.f) - mu*mu;
      float rs = rsqrtf(var + 1e-6f);
      float sc = rs * gs[c];
      scl[t] = sc;
      sft[t] = gb[c] - mu * sc;
    }
    int crow = t >> 2, sch = (t & 3) * 16;
    #pragma unroll
    for (int j = 0; j < 4; j++) {
      float4 v = *(const float4*)&x[(size_t)(c0 + crow)*4096 + s0 + sch + 4*j];
      ts[crow*65 + sch + 4*j + 0] = v.x; ts[crow*65 + sch + 4*j + 1] = v.y;
      ts[crow*65 + sch + 4*j + 2] = v.z; ts[crow*65 + sch + 4*j + 3] = v.w;
    }
    __syncthreads();
    int srow = t >> 2, cch = (t & 3) * 16;
    #pragma unroll
    for (int p = 0; p < 8; p++) {
      int cl = cch + 2*p;
      float f0 = ts[cl*65 + srow] * scl[cl] + sft[cl];
      float f1 = ts[(cl+1)*65 + srow] * scl[cl+1] + sft[cl+1];
      *(unsigned*)&gnT[(size_t)(s0 + srow)*320 + c0 + cl] = pack2(f0, f1);
    }
  } else {
    u16* As = smem;
    u16* Bs = smem + 64*72;
    const int lane = t & 63, w = t >> 6, l16 = lane & 15, g = lane >> 4;
    int local = blockIdx.x - 320;
    const int bm = (local & 1) * 64, bn = (local >> 1) * 64;
    const int m0 = (w & 1) * 32, n0 = (w >> 1) * 32;
    float4v acc[2][2] = {};
    const int ar = t >> 2, ac = (t & 3) * 16;
    const bool aok = (bm + ar) < 77;
    const u16* ga = &ctxb[(size_t)(bm + ar)*768 + ac];
    const u16* gbp = &wk2T[(size_t)(bn + ar)*768 + ac];
    short8v pa0 = {}, pa1 = {}, pb0, pb1;
    if (aok) { pa0 = *(const short8v*)ga; pa1 = *(const short8v*)(ga + 8); }
    pb0 = *(const short8v*)gbp; pb1 = *(const short8v*)(gbp + 8);
    for (int k0 = 0; k0 < 768; k0 += 64) {
      __syncthreads();
      *(short8v*)&As[ar*72 + ac] = pa0;
      *(short8v*)&As[ar*72 + ac + 8] = pa1;
      *(short8v*)&Bs[ar*72 + ac] = pb0;
      *(short8v*)&Bs[ar*72 + ac + 8] = pb1;
      __syncthreads();
      if (k0 + 64 < 768) {
        if (aok) { pa0 = *(const short8v*)(ga + k0 + 64); pa1 = *(const short8v*)(ga + k0 + 72); }
        pb0 = *(const short8v*)(gbp + k0 + 64); pb1 = *(const short8v*)(gbp + k0 + 72);
      }
      #pragma unroll
      for (int ks = 0; ks < 2; ks++) {
        short8v af[2], bfv[2];
        #pragma unroll
        for (int mt = 0; mt < 2; mt++)
          af[mt] = *(const short8v*)&As[(m0 + 16*mt + l16)*72 + ks*32 + g*8];
        #pragma unroll
        for (int nt = 0; nt < 2; nt++)
          bfv[nt] = *(const short8v*)&Bs[(n0 + 16*nt + l16)*72 + ks*32 + g*8];
        #pragma unroll
        for (int mt = 0; mt < 2; mt++)
          #pragma unroll
          for (int nt = 0; nt < 2; nt++)
            acc[mt][nt] = __builtin_amdgcn_mfma_f32_16x16x32_bf16(af[mt], bfv[nt], acc[mt][nt], 0, 0, 0);
      }
    }
    __syncthreads();
    float* Cs = (float*)smem;
    #pragma unroll
    for (int mt = 0; mt < 2; mt++)
      #pragma unroll
      for (int nt = 0; nt < 2; nt++)
        #pragma unroll
        for (int r = 0; r < 4; r++)
          Cs[(m0 + 16*mt + 4*g + r)*68 + n0 + 16*nt + l16] = acc[mt][nt][r];
    __syncthreads();
    u16* C = kcvc + (size_t)(bn / 320) * 24640;
    int nb = bn % 320;
    #pragma unroll
    for (int i = 0; i < 8; i++) {
      int p = t + i*256;
      int mm = p >> 5, nn = (p & 31)*2;
      if (bm + mm >= 77) continue;
      *(unsigned*)&C[(size_t)(bm + mm)*320 + nb + nn] = pack2(Cs[mm*68 + nn], Cs[mm*68 + nn + 1]);
    }
  }
}

// ---------------- LayerNorm bf16->bf16: one wave per row of 320 ----------------
__global__ __launch_bounds__(64) void layernorm_kernel(
    const u16* __restrict__ X, const float* __restrict__ s,
    const float* __restrict__ b, u16* __restrict__ Y) {
  int row = blockIdx.x, t = threadIdx.x;
  const u16* xr = X + (size_t)row*320;
  float v[5], sum = 0.f, sq = 0.f;
  #pragma unroll
  for (int i = 0; i < 5; i++) { v[i] = bfu2f(xr[t + 64*i]); sum += v[i]; sq += v[i]*v[i]; }
  #pragma unroll
  for (int o = 32; o > 0; o >>= 1) { sum += __shfl_down(sum, o); sq += __shfl_down(sq, o); }
  sum = __shfl(sum, 0); sq = __shfl(sq, 0);
  float mu = sum * (1.f/320.f);
  float var = sq * (1.f/320.f) - mu*mu;
  float rs = rsqrtf(var + 1e-5f);
  u16* yr = Y + (size_t)row*320;
  #pragma unroll
  for (int i = 0; i < 5; i++) {
    int c = t + 64*i;
    yr[c] = f2bf((v[i]-mu)*rs*s[c] + b[c]);
  }
}

// ---------------- One-shot GEMM (BM=32): latency-bound N=320 GEMMs -----------------
template<int MODE>
__global__ __launch_bounds__(256) void oneshot(
    const u16* __restrict__ A, const u16* __restrict__ BT,
    const float* __restrict__ bias, const u16* __restrict__ res,
    const float* __restrict__ xres, void* __restrict__ Cout,
    int K, int chunks) {
  __shared__ __align__(16) u16 As[32*328];
  __shared__ __align__(16) u16 Bs[32*328];
  const int t = threadIdx.x;
  const int lane = t & 63, w = t >> 6, l16 = lane & 15, g = lane >> 4;
  const int bm = blockIdx.x * 32, bn = blockIdx.y * 32;
  const int m0 = (w & 1) * 16, n0 = (w >> 1) * 16;
  float4v acc = {};

  const u16* Ab = A + (size_t)(bm + (t>>3))*K + (t&7)*16;
  u16* Al = As + (t>>3)*328 + (t&7)*16;
  const u16* Bb = BT + (size_t)(bn + (t>>3))*K + (t&7)*16;
  u16* Bl = Bs + (t>>3)*328 + (t&7)*16;
  const bool b3 = (t & 7) < 4;

  for (int ch = 0; ch < chunks; ch++) {
    const int c0 = ch*320;
    __syncthreads();
    *(short8v*)Al         = *(const short8v*)(Ab + c0);
    *(short8v*)(Al + 8)   = *(const short8v*)(Ab + c0 + 8);
    *(short8v*)(Al + 128) = *(const short8v*)(Ab + c0 + 128);
    *(short8v*)(Al + 136) = *(const short8v*)(Ab + c0 + 136);
    *(short8v*)Bl         = *(const short8v*)(Bb + c0);
    *(short8v*)(Bl + 8)   = *(const short8v*)(Bb + c0 + 8);
    *(short8v*)(Bl + 128) = *(const short8v*)(Bb + c0 + 128);
    *(short8v*)(Bl + 136) = *(const short8v*)(Bb + c0 + 136);
    if (b3) {
      *(short8v*)(Al + 256) = *(const short8v*)(Ab + c0 + 256);
      *(short8v*)(Al + 264) = *(const short8v*)(Ab + c0 + 264);
      *(short8v*)(Bl + 256) = *(const short8v*)(Bb + c0 + 256);
      *(short8v*)(Bl + 264) = *(const short8v*)(Bb + c0 + 264);
    }
    __syncthreads();
    #pragma unroll
    for (int ks = 0; ks < 10; ks++) {
      short8v bfv = *(const short8v*)&Bs[(n0 + l16)*328 + ks*32 + g*8];
      short8v af  = *(const short8v*)&As[(m0 + l16)*328 + ks*32 + g*8];
      acc = __builtin_amdgcn_mfma_f32_16x16x32_bf16(af, bfv, acc, 0, 0, 0);
    }
  }
  __syncthreads();
  float* Cs = (float*)As;   // [32][36]
  #pragma unroll
  for (int r = 0; r < 4; r++)
    Cs[(m0 + 4*g + r)*36 + n0 + l16] = acc[r];
  __syncthreads();

  if (MODE == 0) {
    u16* C = (u16*)Cout;
    #pragma unroll
    for (int i = 0; i < 2; i++) {
      int p = t + i*256;
      int mm = p >> 4, pp = (p & 15)*2;
      float f0 = Cs[mm*36 + pp], f1 = Cs[mm*36 + pp + 1];
      if (bias) { f0 += bias[bn + pp]; f1 += bias[bn + pp + 1]; }
      if (res) {
        unsigned u = *(const unsigned*)&res[(size_t)(bm + mm)*320 + bn + pp];
        f0 += bfu2f((u16)(u & 0xffffu));
        f1 += bfu2f((u16)(u >> 16));
      }
      *(unsigned*)&C[(size_t)(bm + mm)*320 + bn + pp] = pack2(f0, f1);
    }
  } else {
    float* C = (float*)Cout;
    int nloc = t >> 3, mch = (t & 7) * 4;
    float bb = bias[bn + nloc];
    float4 xv = *(const float4*)&xres[(size_t)(bn + nloc)*4096 + bm + mch];
    float4 ov;
    ov.x = Cs[(mch+0)*36 + nloc] + bb + xv.x;
    ov.y = Cs[(mch+1)*36 + nloc] + bb + xv.y;
    ov.z = Cs[(mch+2)*36 + nloc] + bb + xv.z;
    ov.w = Cs[(mch+3)*36 + nloc] + bb + xv.w;
    *(float4*)&C[(size_t)(bn + nloc)*4096 + bm + mch] = ov;
  }
}

// ---------------- wo_merge: fused [merge 4 attn partials] + wo1 GEMM + residual ----------
// A[m][k] = (sum_sp Opart[sp][m][k]) * invls[m][k/40]; C = A @ wo1T^T + bo1 + res
__global__ __launch_bounds__(256) void wo_merge(
    const u16* __restrict__ Opart, const float* __restrict__ Lp,
    const u16* __restrict__ BT, const float* __restrict__ bias,
    const u16* __restrict__ res, u16* __restrict__ Cout) {
  __shared__ __align__(16) u16 As[32*328];
  __shared__ __align__(16) u16 Bs[32*328];
  __shared__ float invS[32][8];
  const int t = threadIdx.x;
  const int lane = t & 63, w = t >> 6, l16 = lane & 15, g = lane >> 4;
  const int bm = blockIdx.x * 32, bn = blockIdx.y * 32;
  const int m0 = (w & 1) * 16, n0 = (w >> 1) * 16;
  const size_t HBu = 4096u*320u;
  float4v acc = {};

  // per-(row, head) 1/l
  {
    int rr = t >> 3, hh = t & 7;
    int qh = (bm + rr)*8 + hh;
    float ls = Lp[qh] + Lp[32768 + qh] + Lp[2*32768 + qh] + Lp[3*32768 + qh];
    invS[rr][hh] = 1.f / ls;
  }

  // B staging (independent of invS)
  const u16* Bb = BT + (size_t)(bn + (t>>3))*320 + (t&7)*16;
  u16* Bl = Bs + (t>>3)*328 + (t&7)*16;
  const bool b3 = (t & 7) < 4;
  *(short8v*)Bl         = *(const short8v*)Bb;
  *(short8v*)(Bl + 8)   = *(const short8v*)(Bb + 8);
  *(short8v*)(Bl + 128) = *(const short8v*)(Bb + 128);
  *(short8v*)(Bl + 136) = *(const short8v*)(Bb + 136);
  if (b3) {
    *(short8v*)(Bl + 256) = *(const short8v*)(Bb + 256);
    *(short8v*)(Bl + 264) = *(const short8v*)(Bb + 264);
  }
  __syncthreads();   // invS visible

  // A staging: merged+normalized partials, 16-col chunks
  const int r = t >> 3, c0 = (t & 7) * 16;
  #pragma unroll
  for (int cx = 0; cx < 3; cx++) {
    int cc = c0 + cx*128;
    if (cx == 2 && !b3) break;
    float s[16];
    #pragma unroll
    for (int j = 0; j < 16; j++) s[j] = 0.f;
    #pragma unroll
    for (int sp = 0; sp < 4; sp++) {
      const unsigned* p = (const unsigned*)(Opart + (size_t)sp*HBu + (size_t)(bm + r)*320 + cc);
      #pragma unroll
      for (int e = 0; e < 8; e++) {
        unsigned u = p[e];
        s[2*e]   += bfu2f((u16)(u & 0xffffu));
        s[2*e+1] += bfu2f((u16)(u >> 16));
      }
    }
    int h0 = cc / 40;
    int bnd = (h0 + 1) * 40;
    float inv0 = invS[r][h0];
    float inv1 = invS[r][(cc + 15) / 40];
    unsigned o[8];
    #pragma unroll
    for (int e = 0; e < 8; e++) {
      float f0 = s[2*e]   * ((cc + 2*e)     < bnd ? inv0 : inv1);
      float f1 = s[2*e+1] * ((cc + 2*e + 1) < bnd ? inv0 : inv1);
      o[e] = pack2(f0, f1);
    }
    u16* dst = As + r*328 + cc;
    uint4 w0; w0.x = o[0]; w0.y = o[1]; w0.z = o[2]; w0.w = o[3];
    uint4 w1; w1.x = o[4]; w1.y = o[5]; w1.z = o[6]; w1.w = o[7];
    *(uint4*)dst = w0;
    *(uint4*)(dst + 8) = w1;
  }
  __syncthreads();

  #pragma unroll
  for (int ks = 0; ks < 10; ks++) {
    short8v bfv = *(const short8v*)&Bs[(n0 + l16)*328 + ks*32 + g*8];
    short8v af  = *(const short8v*)&As[(m0 + l16)*328 + ks*32 + g*8];
    acc = __builtin_amdgcn_mfma_f32_16x16x32_bf16(af, bfv, acc, 0, 0, 0);
  }
  __syncthreads();
  float* Cs = (float*)As;   // [32][36]
  #pragma unroll
  for (int rr = 0; rr < 4; rr++)
    Cs[(m0 + 4*g + rr)*36 + n0 + l16] = acc[rr];
  __syncthreads();

  #pragma unroll
  for (int i = 0; i < 2; i++) {
    int p = t + i*256;
    int mm = p >> 4, pp = (p & 15)*2;
    float f0 = Cs[mm*36 + pp] + bias[bn + pp];
    float f1 = Cs[mm*36 + pp + 1] + bias[bn + pp + 1];
    unsigned u = *(const unsigned*)&res[(size_t)(bm + mm)*320 + bn + pp];
    f0 += bfu2f((u16)(u & 0xffffu));
    f1 += bfu2f((u16)(u >> 16));
    *(unsigned*)&Cout[(size_t)(bm + mm)*320 + bn + pp] = pack2(f0, f1);
  }
}

// ---------------- QKV one-shot (BM=32): grid (128, 30) ----------
__global__ __launch_bounds__(256) void qkv_oneshot(
    const u16* __restrict__ A, const u16* __restrict__ BT,
    u16* __restrict__ qk, u16* __restrict__ vT, int segStride) {
  __shared__ __align__(16) u16 As[32*328];
  __shared__ __align__(16) u16 Bs[32*328];
  const int t = threadIdx.x;
  const int lane = t & 63, w = t >> 6, l16 = lane & 15, g = lane >> 4;
  const int bm = blockIdx.x * 32, bn = blockIdx.y * 32;
  const int m0 = (w & 1) * 16, n0 = (w >> 1) * 16;
  float4v acc = {};

  const u16* Ab = A + (size_t)(bm + (t>>3))*320 + (t&7)*16;
  u16* Al = As + (t>>3)*328 + (t&7)*16;
  const u16* Bb = BT + (size_t)(bn + (t>>3))*320 + (t&7)*16;
  u16* Bl = Bs + (t>>3)*328 + (t&7)*16;
  const bool b3 = (t & 7) < 4;

  *(short8v*)Al         = *(const short8v*)Ab;
  *(short8v*)(Al + 8)   = *(const short8v*)(Ab + 8);
  *(short8v*)(Al + 128) = *(const short8v*)(Ab + 128);
  *(short8v*)(Al + 136) = *(const short8v*)(Ab + 136);
  *(short8v*)Bl         = *(const short8v*)Bb;
  *(short8v*)(Bl + 8)   = *(const short8v*)(Bb + 8);
  *(short8v*)(Bl + 128) = *(const short8v*)(Bb + 128);
  *(short8v*)(Bl + 136) = *(const short8v*)(Bb + 136);
  if (b3) {
    *(short8v*)(Al + 256) = *(const short8v*)(Ab + 256);
    *(short8v*)(Al + 264) = *(const short8v*)(Ab + 264);
    *(short8v*)(Bl + 256) = *(const short8v*)(Bb + 256);
    *(short8v*)(Bl + 264) = *(const short8v*)(Bb + 264);
  }
  __syncthreads();
  #pragma unroll
  for (int ks = 0; ks < 10; ks++) {
    short8v bfv = *(const short8v*)&Bs[(n0 + l16)*328 + ks*32 + g*8];
    short8v af  = *(const short8v*)&As[(m0 + l16)*328 + ks*32 + g*8];
    acc = __builtin_amdgcn_mfma_f32_16x16x32_bf16(af, bfv, acc, 0, 0, 0);
  }
  __syncthreads();
  float* Cs = (float*)As;   // [32][36]
  #pragma unroll
  for (int r = 0; r < 4; r++)
    Cs[(m0 + 4*g + r)*36 + n0 + l16] = acc[r];
  __syncthreads();

  if (bn < 640) {
    u16* C = qk + (size_t)(bn / 320) * segStride;
    int nb = bn % 320;
    #pragma unroll
    for (int i = 0; i < 2; i++) {
      int p = t + i*256;
      int mm = p >> 4, pp = (p & 15)*2;
      *(unsigned*)&C[(size_t)(bm + mm)*320 + nb + pp] = pack2(Cs[mm*36 + pp], Cs[mm*36 + pp + 1]);
    }
  } else {
    int nloc = t >> 3, mch = (t & 7) * 4;
    int vd = bn - 640 + nloc;
    u16* dst = vT + (size_t)vd*4096 + bm + mch;
    uint2 o0;
    o0.x = pack2(Cs[(mch+0)*36 + nloc], Cs[(mch+1)*36 + nloc]);
    o0.y = pack2(Cs[(mch+2)*36 + nloc], Cs[(mch+3)*36 + nloc]);
    *(uint2*)dst = o0;
  }
}

// ---------------- GEGLU MFMA (BM=32, reg-prefetch): grid (128, 20) ----------------
__global__ __launch_bounds__(256) void geglu_mfma(
    const u16* __restrict__ A, const u16* __restrict__ BT,
    const float* __restrict__ bias, u16* __restrict__ C) {
  __shared__ __align__(16) u16 smem[32*72 + 2*64*72];
  u16* As = smem;
  u16* Ba = smem + 32*72;
  u16* Bg = smem + 32*72 + 64*72;
  const int t = threadIdx.x;
  const int lane = t & 63, w = t >> 6, l16 = lane & 15, g = lane >> 4;
  const int bm = blockIdx.x * 32, bn = blockIdx.y * 64;
  const int m0 = (w & 1) * 16, n0 = (w >> 1) * 32;
  float4v aacc[2] = {}, gacc[2] = {};
  const int arA = t >> 3, acA = (t & 7) * 8;
  const int arB = t >> 2, acB = (t & 3) * 16;
  const u16* ga  = &A[(size_t)(bm + arA)*320 + acA];
  const u16* gba = &BT[(size_t)(bn + arB)*320 + acB];
  const u16* gbg = &BT[(size_t)(1280 + bn + arB)*320 + acB];

  short8v pa0 = *(const short8v*)ga;
  short8v pb0 = *(const short8v*)gba, pb1 = *(const short8v*)(gba + 8);
  short8v pg0 = *(const short8v*)gbg, pg1 = *(const short8v*)(gbg + 8);

  for (int k0 = 0; k0 < 320; k0 += 64) {
    __syncthreads();
    *(short8v*)&As[arA*72 + acA] = pa0;
    *(short8v*)&Ba[arB*72 + acB] = pb0;
    *(short8v*)&Ba[arB*72 + acB + 8] = pb1;
    *(short8v*)&Bg[arB*72 + acB] = pg0;
    *(short8v*)&Bg[arB*72 + acB + 8] = pg1;
    __syncthreads();
    if (k0 + 64 < 320) {
      pa0 = *(const short8v*)(ga + k0 + 64);
      pb0 = *(const short8v*)(gba + k0 + 64); pb1 = *(const short8v*)(gba + k0 + 72);
      pg0 = *(const short8v*)(gbg + k0 + 64); pg1 = *(const short8v*)(gbg + k0 + 72);
    }
    #pragma unroll
    for (int ks = 0; ks < 2; ks++) {
      short8v af = *(const short8v*)&As[(m0 + l16)*72 + ks*32 + g*8];
      #pragma unroll
      for (int nt = 0; nt < 2; nt++) {
        short8v bav = *(const short8v*)&Ba[(n0 + 16*nt + l16)*72 + ks*32 + g*8];
        short8v bgv = *(const short8v*)&Bg[(n0 + 16*nt + l16)*72 + ks*32 + g*8];
        aacc[nt] = __builtin_amdgcn_mfma_f32_16x16x32_bf16(af, bav, aacc[nt], 0, 0, 0);
        gacc[nt] = __builtin_amdgcn_mfma_f32_16x16x32_bf16(af, bgv, gacc[nt], 0, 0, 0);
      }
    }
  }
  __syncthreads();
  float* Cs = (float*)smem;   // [32][68]
  #pragma unroll
  for (int nt = 0; nt < 2; nt++) {
    int col = n0 + 16*nt + l16;
    float ba = bias[bn + col];
    float bg2 = bias[1280 + bn + col];
    #pragma unroll
    for (int r = 0; r < 4; r++) {
      float a = aacc[nt][r] + ba;
      float gv = gacc[nt][r] + bg2;
      float gl = 0.5f * gv * (1.f + erff(gv * 0.70710678118654752f));
      Cs[(m0 + 4*g + r)*68 + col] = a * gl;
    }
  }
  __syncthreads();
  #pragma unroll
  for (int i = 0; i < 4; i++) {
    int p = t + i*256;
    int mm = p >> 5, nn = (p & 31)*2;
    *(unsigned*)&C[(size_t)(bm + mm)*1280 + bn + nn] = pack2(Cs[mm*68 + nn], Cs[mm*68 + nn + 1]);
  }
}

// ---------------- Self-attention partial: ones-row l-via-MFMA, reg-prefetch ----------------
__global__ __launch_bounds__(512) void self_attn_part(
    const u16* __restrict__ Q, const u16* __restrict__ K,
    const u16* __restrict__ vT, u16* __restrict__ Opart,
    float* __restrict__ Lp) {
  const int h = blockIdx.y;
  const int q0 = blockIdx.x * 128;
  const int sp = blockIdx.z;
  const int tid = threadIdx.x;
  const int w = tid >> 6, lane = tid & 63;
  const int l16 = lane & 15, g = lane >> 4;

  __shared__ __align__(16) u16 Kls[64][72];
  __shared__ __align__(16) u16 Vt[48][72];
  __shared__ __align__(16) u16 PsT[8][16][72];

  for (int e = tid; e < 64*12; e += 512) {
    int r = e / 12, c = e % 12;
    *(unsigned*)&Kls[r][40 + 2*c] = 0u;
  }
  if (tid < 256) {
    int r = 40 + (tid >> 5), c = tid & 31;
    *(unsigned*)&Vt[r][2*c] = (r == 40) ? 0x3F803F80u : 0u;
  }

  short8v Qb[2];
  {
    const u16* qrow = Q + (size_t)(q0 + w*16 + l16)*320 + h*40;
    Qb[0] = *(const short8v*)(qrow + g*8);
    short8v z = {};
    Qb[1] = (g == 0) ? *(const short8v*)(qrow + 32) : z;
  }

  const u16* Kbase = K + (size_t)(sp*1024)*320 + h*40;
  const u16* Vbase = vT + (size_t)(h*40)*4096 + sp*1024;

  const int ksl = (tid < 320) ? tid : 0;
  const int keyK = ksl / 5, chK = ksl - keyK*5;
  const u16* gK = Kbase + (size_t)keyK*320 + chK*8;
  u16* lK = &Kls[keyK][chK*8];
  const int vsl = (tid >= 192) ? (tid - 192) : 0;
  const int dV = vsl >> 3, chV = vsl & 7;
  const u16* gV = Vbase + (size_t)dV*4096 + chV*8;
  u16* lV = &Vt[dV][chV*8];

  const bool doK = (tid < 320), doV = (tid >= 192);

  short8v rK = {}, rV = {};
  if (doK) rK = *(const short8v*)gK;
  if (doV) rV = *(const short8v*)gV;
  gK += 64*320; gV += 64;

  float4v Of[3] = {};

  for (int it = 0; it < 16; ++it) {
    __syncthreads();
    if (doK) *(short8v*)lK = rK;
    if (doV) *(short8v*)lV = rV;
    __syncthreads();
    if (it < 15) {
      if (doK) rK = *(const short8v*)gK;
      if (doV) rV = *(const short8v*)gV;
      gK += 64*320; gV += 64;
    }

    float4v Sf[4];
    #pragma unroll
    for (int mt = 0; mt < 4; mt++) {
      short8v ka0 = *(const short8v*)&Kls[mt*16 + l16][g*8];
      short8v ka1 = *(const short8v*)&Kls[mt*16 + l16][32 + g*8];
      float4v s = {};
      s = __builtin_amdgcn_mfma_f32_16x16x32_bf16(ka0, Qb[0], s, 0, 0, 0);
      s = __builtin_amdgcn_mfma_f32_16x16x32_bf16(ka1, Qb[1], s, 0, 0, 0);
      Sf[mt] = s;
    }

    #pragma unroll
    for (int mt = 0; mt < 4; mt++)
      #pragma unroll
      for (int r = 0; r < 4; r++)
        Sf[mt][r] = exp2f(Sf[mt][r]);

    #pragma unroll
    for (int mt = 0; mt < 4; mt++) {
      uint2 pk;
      pk.x = pack2(Sf[mt][0], Sf[mt][1]);
      pk.y = pack2(Sf[mt][2], Sf[mt][3]);
      *(uint2*)&PsT[w][l16][mt*16 + 4*g] = pk;
    }
    asm volatile("s_waitcnt lgkmcnt(0)" ::: "memory");

    #pragma unroll
    for (int ks = 0; ks < 2; ks++) {
      short8v pb = *(const short8v*)&PsT[w][l16][ks*32 + g*8];
      #pragma unroll
      for (int mt = 0; mt < 3; mt++) {
        short8v va = *(const short8v*)&Vt[mt*16 + l16][ks*32 + g*8];
        Of[mt] = __builtin_amdgcn_mfma_f32_16x16x32_bf16(va, pb, Of[mt], 0, 0, 0);
      }
    }
  }

  const int q = q0 + w*16 + l16;
  u16* orow = Opart + (size_t)sp*4096*320 + (size_t)q*320 + h*40;
  #pragma unroll
  for (int mt = 0; mt < 3; mt++) {
    #pragma unroll
    for (int rp = 0; rp < 2; rp++) {
      int d = mt*16 + 4*g + rp*2;
      if (d < 40)
        *(unsigned*)&orow[d] = pack2(Of[mt][rp*2], Of[mt][rp*2+1]);
    }
  }
  if (g == 2)
    Lp[sp*32768 + q*8 + h] = Of[2][0];
}

// ---------------- Cross-attention: single-shot MFMA, 77 keys, max-free ----------------
__global__ __launch_bounds__(256) void cross_attn_mfma(
    const u16* __restrict__ Q, const u16* __restrict__ Kc,
    const u16* __restrict__ Vc, u16* __restrict__ O) {
  const int h = blockIdx.y;
  const int q0 = blockIdx.x * 64;
  const int tid = threadIdx.x;
  const int w = tid >> 6, lane = tid & 63;
  const int l16 = lane & 15, g = lane >> 4;

  __shared__ __align__(16) u16 Kls[80][72];
  __shared__ __align__(16) u16 Vt[48][104];
  __shared__ __align__(16) u16 PsT[4][16][104];

  for (int e = tid; e < 80*12; e += 256) {
    int r = e / 12, c = e % 12;
    *(unsigned*)&Kls[r][40 + 2*c] = 0u;
  }
  for (int e = tid; e < 48*52; e += 256) {
    int r = e / 52, c = e % 52;
    *(unsigned*)&Vt[r][2*c] = 0u;
  }
  {
    int r = lane >> 2, c4 = (lane & 3)*4;
    uint2 z; z.x = 0u; z.y = 0u;
    *(uint2*)&PsT[w][r][80 + c4] = z;
  }

  short8v Qb[2];
  {
    const u16* qrow = Q + (size_t)(q0 + w*16 + l16)*320 + h*40;
    Qb[0] = *(const short8v*)(qrow + g*8);
    short8v z = {};
    Qb[1] = (g == 0) ? *(const short8v*)(qrow + 32) : z;
  }

  for (int e = tid; e < 1600; e += 256) {
    int key = e / 20, dp = e % 20;
    unsigned val = 0u;
    if (key < 77) val = *(const unsigned*)&Kc[(size_t)key*320 + h*40 + dp*2];
    *(unsigned*)&Kls[key][dp*2] = val;
  }
  __syncthreads();
  for (int e = tid; e < 1600; e += 256) {
    int kp = e / 40, d = e % 40;
    unsigned u0 = (kp*2     < 77) ? (unsigned)Vc[(size_t)(kp*2    )*320 + h*40 + d] : 0u;
    unsigned u1 = (kp*2 + 1 < 77) ? (unsigned)Vc[(size_t)(kp*2 + 1)*320 + h*40 + d] : 0u;
    *(unsigned*)&Vt[d][kp*2] = u0 | (u1 << 16);
  }
  __syncthreads();

  float4v Sf[5];
  #pragma unroll
  for (int mt = 0; mt < 5; mt++) {
    short8v ka0 = *(const short8v*)&Kls[mt*16 + l16][g*8];
    short8v ka1 = *(const short8v*)&Kls[mt*16 + l16][32 + g*8];
    float4v s = {};
    s = __builtin_amdgcn_mfma_f32_16x16x32_bf16(ka0, Qb[0], s, 0, 0, 0);
    s = __builtin_amdgcn_mfma_f32_16x16x32_bf16(ka1, Qb[1], s, 0, 0, 0);
    Sf[mt] = s;
  }

  float rsum = 0.f;
  #pragma unroll
  for (int mt = 0; mt < 5; mt++)
    #pragma unroll
    for (int r = 0; r < 4; r++) {
      int key = mt*16 + 4*g + r;
      float p = (key < 77) ? exp2f(Sf[mt][r]) : 0.f;
      Sf[mt][r] = p; rsum += p;
    }
  rsum += __shfl_xor(rsum, 16);
  rsum += __shfl_xor(rsum, 32);

  #pragma unroll
  for (int mt = 0; mt < 5; mt++) {
    uint2 pk;
    pk.x = pack2(Sf[mt][0], Sf[mt][1]);
    pk.y = pack2(Sf[mt][2], Sf[mt][3]);
    *(uint2*)&PsT[w][l16][mt*16 + 4*g] = pk;
  }
  __syncthreads();

  float4v Of[3] = {};
  #pragma unroll
  for (int ks = 0; ks < 3; ks++) {
    short8v pb = *(const short8v*)&PsT[w][l16][ks*32 + g*8];
    #pragma unroll
    for (int mt = 0; mt < 3; mt++) {
      short8v va = *(const short8v*)&Vt[mt*16 + l16][ks*32 + g*8];
      Of[mt] = __builtin_amdgcn_mfma_f32_16x16x32_bf16(va, pb, Of[mt], 0, 0, 0);
    }
  }

  float inv = 1.f / rsum;
  u16* orow = O + (size_t)(q0 + w*16 + l16)*320 + h*40;
  #pragma unroll
  for (int mt = 0; mt < 3; mt++) {
    #pragma unroll
    for (int rp = 0; rp < 2; rp++) {
      int d = mt*16 + 4*g + rp*2;
      if (d < 40)
        *(unsigned*)&orow[d] = pack2(Of[mt][rp*2] * inv, Of[mt][rp*2+1] * inv);
    }
  }
}

extern "C" void kernel_launch(void* const* d_in, const int* in_sizes, int n_in,
                              void* d_out, int out_size, void* d_ws, size_t ws_size,
                              hipStream_t stream) {
  const float* x        = (const float*)d_in[0];
  const float* ctx      = (const float*)d_in[1];
  const float* gn_s     = (const float*)d_in[2];
  const float* gn_b     = (const float*)d_in[3];
  const float* w_pin    = (const float*)d_in[4];
  const float* b_pin    = (const float*)d_in[5];
  const float* ln1_s    = (const float*)d_in[6];
  const float* ln1_b    = (const float*)d_in[7];
  const float* wq1      = (const float*)d_in[8];
  const float* wk1      = (const float*)d_in[9];
  const float* wv1      = (const float*)d_in[10];
  const float* wo1      = (const float*)d_in[11];
  const float* bo1      = (const float*)d_in[12];
  const float* ln2_s    = (const float*)d_in[13];
  const float* ln2_b    = (const float*)d_in[14];
  const float* wq2      = (const float*)d_in[15];
  const float* wk2      = (const float*)d_in[16];
  const float* wv2      = (const float*)d_in[17];
  const float* wo2      = (const float*)d_in[18];
  const float* bo2      = (const float*)d_in[19];
  const float* ln3_s    = (const float*)d_in[20];
  const float* ln3_b    = (const float*)d_in[21];
  const float* w_ff1    = (const float*)d_in[22];
  const float* b_ff1    = (const float*)d_in[23];
  const float* w_ff2    = (const float*)d_in[24];
  const float* b_ff2    = (const float*)d_in[25];
  const float* w_pout   = (const float*)d_in[26];
  const float* b_pout   = (const float*)d_in[27];
  float* out = (float*)d_out;

  u16* ws = (u16*)d_ws;
  const size_t HB = 4096u*320u;
  u16* h   = ws;
  u16* hn  = ws + HB;
  u16* q   = ws + 2*HB;    // q,k contiguous (QKV fused epilogue)
  u16* k   = ws + 3*HB;
  u16* vT  = ws + 4*HB;    // V^T [320][4096]
  u16* ao  = ws + 5*HB;
  u16* gnT = k;
  u16* gg  = q;            // GEGLU out overlays q,k,vT,ao
  u16* wb  = ws + 6*HB;
  size_t o = 0;
  u16* ctxb   = wb + o; o += 59136;
  u16* wq1T   = wb + o; o += 102400;   // stacked: wq1T,wk1T,wv1T = [960][320]
  u16* wk1T   = wb + o; o += 102400;
  u16* wv1T   = wb + o; o += 102400;
  u16* wo1T   = wb + o; o += 102400;
  u16* wq2T   = wb + o; o += 102400;
  u16* wk2T   = wb + o; o += 245760;   // stacked: wk2T,wv2T = [640][768]
  u16* wv2T   = wb + o; o += 245760;
  u16* wo2T   = wb + o; o += 102400;
  u16* wff1T  = wb + o; o += 819200;
  u16* wff2T  = wb + o; o += 409600;
  u16* wpoutT = wb + o; o += 102400;
  u16* wpinT  = wb + o; o += 102400;
  u16* kc     = wb + o; o += 24640;    // kc,vc contiguous
  u16* vc     = wb + o; o += 24640;
  float* psum = (float*)(wb + o);      // 256 partial sums
  float* psq  = psum + 256;
  u16* OpartB = (u16*)(psq + 256);               // 4 x HB bf16 = 10.5 MB
  float* Lpart = (float*)(OpartB + 4*HB);        // 4 x 32768 fp32

  TPack tp;
  const float* srcs[12] = {wq1, wk1, wv1, wo1, wq2, wo2, w_pin, w_pout, wk2, wv2, w_ff1, w_ff2};
  u16* dsts[12]         = {wq1T, wk1T, wv1T, wo1T, wq2T, wo2T, wpinT, wpoutT, wk2T, wv2T, wff1T, wff2T};
  int Ks[12] = {320,320,320,320,320,320,320,320,768,768,320,1280};
  int Ns[12] = {320,320,320,320,320,320,320,320,320,320,2560,320};
  int off = 0;
  for (int i = 0; i < 12; i++) {
    tp.d[i].src = srcs[i]; tp.d[i].dst = dsts[i];
    tp.d[i].K = Ks[i]; tp.d[i].N = Ns[i];
    tp.d[i].off = off; tp.d[i].tx = Ns[i]/32;
    tp.d[i].sc = (i == 0 || i == 4) ? SCALE_L2E : 1.0f;   // wq1, wq2 pre-scaled
    off += (Ks[i]/32)*(Ns[i]/32);
  }

  dim3 blk(256), g128x10(128, 10);
  const u16* nres = nullptr;
  const float* nb = nullptr;

  // prep: weight tcvt (off) + ctx cvt (58) + gn partial stats (256)
  hipLaunchKernelGGL(prep_kernel, dim3(off + 58 + 256), blk, 0, stream,
                     tp, off, ctx, ctxb, x, psum, psq);
  // fused: gn apply+transpose (320 blocks) || kc/vc GEMM (20 blocks)
  hipLaunchKernelGGL(gn_kcvc, dim3(340), blk, 0, stream,
                     x, psum, psq, gn_s, gn_b, gnT, ctxb, wk2T, kc);
  hipLaunchKernelGGL((oneshot<0>), g128x10, blk, 0, stream, gnT, wpinT, b_pin, nres, nb, (void*)h, 320, 1);
  hipLaunchKernelGGL(layernorm_kernel, dim3(4096), dim3(64), 0, stream, h, ln1_s, ln1_b, hn);
  // fused QKV one-shot: grid (128,30); segs 0,1 -> q,k; seg 2 -> vT
  hipLaunchKernelGGL(qkv_oneshot, dim3(128, 30), blk, 0, stream, hn, wq1T, q, vT, (int)HB);
  hipLaunchKernelGGL(self_attn_part, dim3(32, 8, 4), dim3(512), 0, stream, q, k, vT, OpartB, Lpart);
  // fused merge(4 partials)+wo1+residual: replaces attn_merge + wo1 oneshot
  hipLaunchKernelGGL(wo_merge, g128x10, blk, 0, stream, OpartB, Lpart, wo1T, bo1, h, h);
  hipLaunchKernelGGL(layernorm_kernel, dim3(4096), dim3(64), 0, stream, h, ln2_s, ln2_b, hn);
  hipLaunchKernelGGL((oneshot<0>), g128x10, blk, 0, stream, hn, wq2T, nb, nres, nb, (void*)q, 320, 1);
  hipLaunchKernelGGL(cross_attn_mfma, dim3(64, 8), blk, 0, stream, q, kc, vc, ao);
  hipLaunchKernelGGL((oneshot<0>), g128x10, blk, 0, stream, ao, wo2T, bo2, h, nb, (void*)h, 320, 1);
  hipLaunchKernelGGL(layernorm_kernel, dim3(4096), dim3(64), 0, stream, h, ln3_s, ln3_b, hn);
  hipLaunchKernelGGL(geglu_mfma, dim3(128, 20), blk, 0, stream, hn, wff1T, b_ff1, gg);
  hipLaunchKernelGGL((oneshot<0>), g128x10, blk, 0, stream, gg, wff2T, b_ff2, h, nb, (void*)h, 1280, 4);
  hipLaunchKernelGGL((oneshot<2>), g128x10, blk, 0, stream, h, wpoutT, b_pout, nres, x, (void*)out, 320, 1);
}

// Round 19
// 286.318 us; speedup vs baseline: 1.0082x; 1.0082x over previous
//
#include <hip/hip_runtime.h>
#include <hip/hip_bf16.h>
#include <math.h>

#define SCALE_L2E  0.22811011265722836f   // (1/sqrt(40)) * log2(e)

typedef __attribute__((ext_vector_type(8))) short short8v;
typedef __attribute__((ext_vector_type(4))) float float4v;
typedef unsigned short u16;

__device__ __forceinline__ unsigned pack2(float a, float b) {
  float2 f; f.x = a; f.y = b;
  __hip_bfloat162 h = __float22bfloat162_rn(f);
  return *(unsigned*)&h;
}
__device__ __forceinline__ float bfu2f(u16 u) {
  return __uint_as_float(((unsigned)u) << 16);
}
__device__ __forceinline__ u16 f2bf(float x) {
  __hip_bfloat16 h = __float2bfloat16(x);
  return *(u16*)&h;
}

// ---------------- prep: weight transpose+convert | ctx cvt | gn PARTIAL stats --------------
struct TDesc { const float* src; u16* dst; int K, N, off, tx; float sc; };
struct TPack { TDesc d[12]; };

__global__ __launch_bounds__(256) void prep_kernel(
    TPack p, int nT,
    const float* __restrict__ ctxsrc, u16* __restrict__ ctxdst,
    const float* __restrict__ x,
    float* __restrict__ psum, float* __restrict__ psq) {
  __shared__ float ls[32][33];
  int bt = blockIdx.x, t = threadIdx.x;
  if (bt < nT) {
    int ti = 0;
    #pragma unroll
    for (int i = 1; i < 12; i++) if (bt >= p.d[i].off) ti = i;
    TDesc dd = p.d[ti];
    int local = bt - dd.off;
    int n0 = (local % dd.tx) * 32, k0 = (local / dd.tx) * 32;
    #pragma unroll
    for (int i = 0; i < 4; i++) {
      int idx = t + i*256, r = idx >> 5, c = idx & 31;
      ls[r][c] = dd.src[(size_t)(k0 + r)*dd.N + n0 + c];
    }
    __syncthreads();
    #pragma unroll
    for (int i = 0; i < 2; i++) {
      int p2 = t + i*256, n = p2 >> 4, kp = (p2 & 15)*2;
      *(unsigned*)&dd.dst[(size_t)(n0 + n)*dd.K + k0 + kp] =
        pack2(ls[kp][n]*dd.sc, ls[kp+1][n]*dd.sc);
    }
  } else if (bt < nT + 58) {
    int idx = ((bt - nT)*256 + t)*4;
    if (idx < 59136) {
      float4 v = *(const float4*)&ctxsrc[idx];
      uint2 o; o.x = pack2(v.x, v.y); o.y = pack2(v.z, v.w);
      *(uint2*)&ctxdst[idx] = o;
    }
  } else {
    int pp = bt - nT - 58;            // 0..255
    int g = pp >> 3, part = pp & 7;
    size_t base = (size_t)g*40960 + (size_t)part*5120;
    float sum = 0.f, sq = 0.f;
    #pragma unroll
    for (int r = 0; r < 5; r++) {
      float4 v = *(const float4*)&x[base + (size_t)(t + r*256)*4];
      sum += v.x + v.y + v.z + v.w;
      sq  += v.x*v.x + v.y*v.y + v.z*v.z + v.w*v.w;
    }
    float* s1 = &ls[0][0];
    float* s2 = &ls[8][0] + 8;
    s1[t] = sum; s2[t] = sq; __syncthreads();
    for (int st = 128; st > 0; st >>= 1) {
      if (t < st) { s1[t] += s1[t+st]; s2[t] += s2[t+st]; }
      __syncthreads();
    }
    if (t == 0) { psum[pp] = s1[0]; psq[pp] = s2[0]; }
  }
}

// ---------------- fused: GN apply+transpose (blocks 0..319) | kc/vc GEMM (320..339) --------
__global__ __launch_bounds__(256) void gn_kcvc(
    const float* __restrict__ x, const float* __restrict__ psum,
    const float* __restrict__ psq, const float* __restrict__ gs,
    const float* __restrict__ gb, u16* __restrict__ gnT,
    const u16* __restrict__ ctxb, const u16* __restrict__ wk2T,
    u16* __restrict__ kcvc) {
  __shared__ __align__(16) u16 smem[2*64*72];
  __shared__ float scl[64], sft[64];
  const int t = threadIdx.x;
  if (blockIdx.x < 320) {
    float* ts = (float*)smem;
    int s0 = (blockIdx.x & 63) * 64, c0 = (blockIdx.x >> 6) * 64;
    if (t < 64) {
      int c = c0 + t, g = c / 10;
      float s = 0.f, q = 0.f;
      #pragma unroll
      for (int i = 0; i < 8; i++) { s += psum[g*8 + i]; q += psq[g*8 + i]; }
      float mu = s * (1.f/40960.f);
      float var = q * (1.f/40960.f) - mu*mu;
      float rs = rsqrtf(var + 1e-6f);
      float sc = rs * gs[c];
      scl[t] = sc;
      sft[t] = gb[c] - mu * sc;
    }
    int crow = t >> 2, sch = (t & 3) * 16;
    #pragma unroll
    for (int j = 0; j < 4; j++) {
      float4 v = *(const float4*)&x[(size_t)(c0 + crow)*4096 + s0 + sch + 4*j];
      ts[crow*65 + sch + 4*j + 0] = v.x; ts[crow*65 + sch + 4*j + 1] = v.y;
      ts[crow*65 + sch + 4*j + 2] = v.z; ts[crow*65 + sch + 4*j + 3] = v.w;
    }
    __syncthreads();
    int srow = t >> 2, cch = (t & 3) * 16;
    #pragma unroll
    for (int p = 0; p < 8; p++) {
      int cl = cch + 2*p;
      float f0 = ts[cl*65 + srow] * scl[cl] + sft[cl];
      float f1 = ts[(cl+1)*65 + srow] * scl[cl+1] + sft[cl+1];
      *(unsigned*)&gnT[(size_t)(s0 + srow)*320 + c0 + cl] = pack2(f0, f1);
    }
  } else {
    u16* As = smem;
    u16* Bs = smem + 64*72;
    const int lane = t & 63, w = t >> 6, l16 = lane & 15, g = lane >> 4;
    int local = blockIdx.x - 320;
    const int bm = (local & 1) * 64, bn = (local >> 1) * 64;
    const int m0 = (w & 1) * 32, n0 = (w >> 1) * 32;
    float4v acc[2][2] = {};
    const int ar = t >> 2, ac = (t & 3) * 16;
    const bool aok = (bm + ar) < 77;
    const u16* ga = &ctxb[(size_t)(bm + ar)*768 + ac];
    const u16* gbp = &wk2T[(size_t)(bn + ar)*768 + ac];
    short8v pa0 = {}, pa1 = {}, pb0, pb1;
    if (aok) { pa0 = *(const short8v*)ga; pa1 = *(const short8v*)(ga + 8); }
    pb0 = *(const short8v*)gbp; pb1 = *(const short8v*)(gbp + 8);
    for (int k0 = 0; k0 < 768; k0 += 64) {
      __syncthreads();
      *(short8v*)&As[ar*72 + ac] = pa0;
      *(short8v*)&As[ar*72 + ac + 8] = pa1;
      *(short8v*)&Bs[ar*72 + ac] = pb0;
      *(short8v*)&Bs[ar*72 + ac + 8] = pb1;
      __syncthreads();
      if (k0 + 64 < 768) {
        if (aok) { pa0 = *(const short8v*)(ga + k0 + 64); pa1 = *(const short8v*)(ga + k0 + 72); }
        pb0 = *(const short8v*)(gbp + k0 + 64); pb1 = *(const short8v*)(gbp + k0 + 72);
      }
      #pragma unroll
      for (int ks = 0; ks < 2; ks++) {
        short8v af[2], bfv[2];
        #pragma unroll
        for (int mt = 0; mt < 2; mt++)
          af[mt] = *(const short8v*)&As[(m0 + 16*mt + l16)*72 + ks*32 + g*8];
        #pragma unroll
        for (int nt = 0; nt < 2; nt++)
          bfv[nt] = *(const short8v*)&Bs[(n0 + 16*nt + l16)*72 + ks*32 + g*8];
        #pragma unroll
        for (int mt = 0; mt < 2; mt++)
          #pragma unroll
          for (int nt = 0; nt < 2; nt++)
            acc[mt][nt] = __builtin_amdgcn_mfma_f32_16x16x32_bf16(af[mt], bfv[nt], acc[mt][nt], 0, 0, 0);
      }
    }
    __syncthreads();
    float* Cs = (float*)smem;
    #pragma unroll
    for (int mt = 0; mt < 2; mt++)
      #pragma unroll
      for (int nt = 0; nt < 2; nt++)
        #pragma unroll
        for (int r = 0; r < 4; r++)
          Cs[(m0 + 16*mt + 4*g + r)*68 + n0 + 16*nt + l16] = acc[mt][nt][r];
    __syncthreads();
    u16* C = kcvc + (size_t)(bn / 320) * 24640;
    int nb = bn % 320;
    #pragma unroll
    for (int i = 0; i < 8; i++) {
      int p = t + i*256;
      int mm = p >> 5, nn = (p & 31)*2;
      if (bm + mm >= 77) continue;
      *(unsigned*)&C[(size_t)(bm + mm)*320 + nb + nn] = pack2(Cs[mm*68 + nn], Cs[mm*68 + nn + 1]);
    }
  }
}

// ---------------- LayerNorm bf16->bf16: one wave per row of 320 ----------------
__global__ __launch_bounds__(64) void layernorm_kernel(
    const u16* __restrict__ X, const float* __restrict__ s,
    const float* __restrict__ b, u16* __restrict__ Y) {
  int row = blockIdx.x, t = threadIdx.x;
  const u16* xr = X + (size_t)row*320;
  float v[5], sum = 0.f, sq = 0.f;
  #pragma unroll
  for (int i = 0; i < 5; i++) { v[i] = bfu2f(xr[t + 64*i]); sum += v[i]; sq += v[i]*v[i]; }
  #pragma unroll
  for (int o = 32; o > 0; o >>= 1) { sum += __shfl_down(sum, o); sq += __shfl_down(sq, o); }
  sum = __shfl(sum, 0); sq = __shfl(sq, 0);
  float mu = sum * (1.f/320.f);
  float var = sq * (1.f/320.f) - mu*mu;
  float rs = rsqrtf(var + 1e-5f);
  u16* yr = Y + (size_t)row*320;
  #pragma unroll
  for (int i = 0; i < 5; i++) {
    int c = t + 64*i;
    yr[c] = f2bf((v[i]-mu)*rs*s[c] + b[c]);
  }
}

// ---------------- One-shot GEMM (BM=32): C[M,320] = A[M,K] * BT[320,K]^T -----------------
template<int MODE>
__global__ __launch_bounds__(256) void oneshot(
    const u16* __restrict__ A, const u16* __restrict__ BT,
    const float* __restrict__ bias, const u16* __restrict__ res,
    const float* __restrict__ xres, void* __restrict__ Cout,
    int K, int chunks) {
  __shared__ __align__(16) u16 As[32*328];
  __shared__ __align__(16) u16 Bs[32*328];
  const int t = threadIdx.x;
  const int lane = t & 63, w = t >> 6, l16 = lane & 15, g = lane >> 4;
  const int bm = blockIdx.x * 32, bn = blockIdx.y * 32;
  const int m0 = (w & 1) * 16, n0 = (w >> 1) * 16;
  float4v acc = {};

  const u16* Ab = A + (size_t)(bm + (t>>3))*K + (t&7)*16;
  u16* Al = As + (t>>3)*328 + (t&7)*16;
  const u16* Bb = BT + (size_t)(bn + (t>>3))*K + (t&7)*16;
  u16* Bl = Bs + (t>>3)*328 + (t&7)*16;
  const bool b3 = (t & 7) < 4;

  for (int ch = 0; ch < chunks; ch++) {
    const int c0 = ch*320;
    __syncthreads();
    *(short8v*)Al         = *(const short8v*)(Ab + c0);
    *(short8v*)(Al + 8)   = *(const short8v*)(Ab + c0 + 8);
    *(short8v*)(Al + 128) = *(const short8v*)(Ab + c0 + 128);
    *(short8v*)(Al + 136) = *(const short8v*)(Ab + c0 + 136);
    *(short8v*)Bl         = *(const short8v*)(Bb + c0);
    *(short8v*)(Bl + 8)   = *(const short8v*)(Bb + c0 + 8);
    *(short8v*)(Bl + 128) = *(const short8v*)(Bb + c0 + 128);
    *(short8v*)(Bl + 136) = *(const short8v*)(Bb + c0 + 136);
    if (b3) {
      *(short8v*)(Al + 256) = *(const short8v*)(Ab + c0 + 256);
      *(short8v*)(Al + 264) = *(const short8v*)(Ab + c0 + 264);
      *(short8v*)(Bl + 256) = *(const short8v*)(Bb + c0 + 256);
      *(short8v*)(Bl + 264) = *(const short8v*)(Bb + c0 + 264);
    }
    __syncthreads();
    #pragma unroll
    for (int ks = 0; ks < 10; ks++) {
      short8v bfv = *(const short8v*)&Bs[(n0 + l16)*328 + ks*32 + g*8];
      short8v af  = *(const short8v*)&As[(m0 + l16)*328 + ks*32 + g*8];
      acc = __builtin_amdgcn_mfma_f32_16x16x32_bf16(af, bfv, acc, 0, 0, 0);
    }
  }
  __syncthreads();
  float* Cs = (float*)As;   // [32][36]
  #pragma unroll
  for (int r = 0; r < 4; r++)
    Cs[(m0 + 4*g + r)*36 + n0 + l16] = acc[r];
  __syncthreads();

  if (MODE == 0) {
    u16* C = (u16*)Cout;
    #pragma unroll
    for (int i = 0; i < 2; i++) {
      int p = t + i*256;
      int mm = p >> 4, pp = (p & 15)*2;
      float f0 = Cs[mm*36 + pp], f1 = Cs[mm*36 + pp + 1];
      if (bias) { f0 += bias[bn + pp]; f1 += bias[bn + pp + 1]; }
      if (res) {
        unsigned u = *(const unsigned*)&res[(size_t)(bm + mm)*320 + bn + pp];
        f0 += bfu2f((u16)(u & 0xffffu));
        f1 += bfu2f((u16)(u >> 16));
      }
      *(unsigned*)&C[(size_t)(bm + mm)*320 + bn + pp] = pack2(f0, f1);
    }
  } else {
    float* C = (float*)Cout;
    int nloc = t >> 3, mch = (t & 7) * 4;
    float bb = bias[bn + nloc];
    float4 xv = *(const float4*)&xres[(size_t)(bn + nloc)*4096 + bm + mch];
    float4 ov;
    ov.x = Cs[(mch+0)*36 + nloc] + bb + xv.x;
    ov.y = Cs[(mch+1)*36 + nloc] + bb + xv.y;
    ov.z = Cs[(mch+2)*36 + nloc] + bb + xv.z;
    ov.w = Cs[(mch+3)*36 + nloc] + bb + xv.w;
    *(float4*)&C[(size_t)(bn + nloc)*4096 + bm + mch] = ov;
  }
}

// ---------------- QKV one-shot (BM=32): grid (128, 30) ----------
__global__ __launch_bounds__(256) void qkv_oneshot(
    const u16* __restrict__ A, const u16* __restrict__ BT,
    u16* __restrict__ qk, u16* __restrict__ vT, int segStride) {
  __shared__ __align__(16) u16 As[32*328];
  __shared__ __align__(16) u16 Bs[32*328];
  const int t = threadIdx.x;
  const int lane = t & 63, w = t >> 6, l16 = lane & 15, g = lane >> 4;
  const int bm = blockIdx.x * 32, bn = blockIdx.y * 32;
  const int m0 = (w & 1) * 16, n0 = (w >> 1) * 16;
  float4v acc = {};

  const u16* Ab = A + (size_t)(bm + (t>>3))*320 + (t&7)*16;
  u16* Al = As + (t>>3)*328 + (t&7)*16;
  const u16* Bb = BT + (size_t)(bn + (t>>3))*320 + (t&7)*16;
  u16* Bl = Bs + (t>>3)*328 + (t&7)*16;
  const bool b3 = (t & 7) < 4;

  *(short8v*)Al         = *(const short8v*)Ab;
  *(short8v*)(Al + 8)   = *(const short8v*)(Ab + 8);
  *(short8v*)(Al + 128) = *(const short8v*)(Ab + 128);
  *(short8v*)(Al + 136) = *(const short8v*)(Ab + 136);
  *(short8v*)Bl         = *(const short8v*)Bb;
  *(short8v*)(Bl + 8)   = *(const short8v*)(Bb + 8);
  *(short8v*)(Bl + 128) = *(const short8v*)(Bb + 128);
  *(short8v*)(Bl + 136) = *(const short8v*)(Bb + 136);
  if (b3) {
    *(short8v*)(Al + 256) = *(const short8v*)(Ab + 256);
    *(short8v*)(Al + 264) = *(const short8v*)(Ab + 264);
    *(short8v*)(Bl + 256) = *(const short8v*)(Bb + 256);
    *(short8v*)(Bl + 264) = *(const short8v*)(Bb + 264);
  }
  __syncthreads();
  #pragma unroll
  for (int ks = 0; ks < 10; ks++) {
    short8v bfv = *(const short8v*)&Bs[(n0 + l16)*328 + ks*32 + g*8];
    short8v af  = *(const short8v*)&As[(m0 + l16)*328 + ks*32 + g*8];
    acc = __builtin_amdgcn_mfma_f32_16x16x32_bf16(af, bfv, acc, 0, 0, 0);
  }
  __syncthreads();
  float* Cs = (float*)As;   // [32][36]
  #pragma unroll
  for (int r = 0; r < 4; r++)
    Cs[(m0 + 4*g + r)*36 + n0 + l16] = acc[r];
  __syncthreads();

  if (bn < 640) {
    u16* C = qk + (size_t)(bn / 320) * segStride;
    int nb = bn % 320;
    #pragma unroll
    for (int i = 0; i < 2; i++) {
      int p = t + i*256;
      int mm = p >> 4, pp = (p & 15)*2;
      *(unsigned*)&C[(size_t)(bm + mm)*320 + nb + pp] = pack2(Cs[mm*36 + pp], Cs[mm*36 + pp + 1]);
    }
  } else {
    int nloc = t >> 3, mch = (t & 7) * 4;
    int vd = bn - 640 + nloc;
    u16* dst = vT + (size_t)vd*4096 + bm + mch;
    uint2 o0;
    o0.x = pack2(Cs[(mch+0)*36 + nloc], Cs[(mch+1)*36 + nloc]);
    o0.y = pack2(Cs[(mch+2)*36 + nloc], Cs[(mch+3)*36 + nloc]);
    *(uint2*)dst = o0;
  }
}

// ---------------- GEGLU MFMA (BM=32, reg-prefetch): grid (128, 20) ----------------
__global__ __launch_bounds__(256) void geglu_mfma(
    const u16* __restrict__ A, const u16* __restrict__ BT,
    const float* __restrict__ bias, u16* __restrict__ C) {
  __shared__ __align__(16) u16 smem[32*72 + 2*64*72];
  u16* As = smem;
  u16* Ba = smem + 32*72;
  u16* Bg = smem + 32*72 + 64*72;
  const int t = threadIdx.x;
  const int lane = t & 63, w = t >> 6, l16 = lane & 15, g = lane >> 4;
  const int bm = blockIdx.x * 32, bn = blockIdx.y * 64;
  const int m0 = (w & 1) * 16, n0 = (w >> 1) * 32;
  float4v aacc[2] = {}, gacc[2] = {};
  const int arA = t >> 3, acA = (t & 7) * 8;
  const int arB = t >> 2, acB = (t & 3) * 16;
  const u16* ga  = &A[(size_t)(bm + arA)*320 + acA];
  const u16* gba = &BT[(size_t)(bn + arB)*320 + acB];
  const u16* gbg = &BT[(size_t)(1280 + bn + arB)*320 + acB];

  short8v pa0 = *(const short8v*)ga;
  short8v pb0 = *(const short8v*)gba, pb1 = *(const short8v*)(gba + 8);
  short8v pg0 = *(const short8v*)gbg, pg1 = *(const short8v*)(gbg + 8);

  for (int k0 = 0; k0 < 320; k0 += 64) {
    __syncthreads();
    *(short8v*)&As[arA*72 + acA] = pa0;
    *(short8v*)&Ba[arB*72 + acB] = pb0;
    *(short8v*)&Ba[arB*72 + acB + 8] = pb1;
    *(short8v*)&Bg[arB*72 + acB] = pg0;
    *(short8v*)&Bg[arB*72 + acB + 8] = pg1;
    __syncthreads();
    if (k0 + 64 < 320) {
      pa0 = *(const short8v*)(ga + k0 + 64);
      pb0 = *(const short8v*)(gba + k0 + 64); pb1 = *(const short8v*)(gba + k0 + 72);
      pg0 = *(const short8v*)(gbg + k0 + 64); pg1 = *(const short8v*)(gbg + k0 + 72);
    }
    #pragma unroll
    for (int ks = 0; ks < 2; ks++) {
      short8v af = *(const short8v*)&As[(m0 + l16)*72 + ks*32 + g*8];
      #pragma unroll
      for (int nt = 0; nt < 2; nt++) {
        short8v bav = *(const short8v*)&Ba[(n0 + 16*nt + l16)*72 + ks*32 + g*8];
        short8v bgv = *(const short8v*)&Bg[(n0 + 16*nt + l16)*72 + ks*32 + g*8];
        aacc[nt] = __builtin_amdgcn_mfma_f32_16x16x32_bf16(af, bav, aacc[nt], 0, 0, 0);
        gacc[nt] = __builtin_amdgcn_mfma_f32_16x16x32_bf16(af, bgv, gacc[nt], 0, 0, 0);
      }
    }
  }
  __syncthreads();
  float* Cs = (float*)smem;   // [32][68]
  #pragma unroll
  for (int nt = 0; nt < 2; nt++) {
    int col = n0 + 16*nt + l16;
    float ba = bias[bn + col];
    float bg2 = bias[1280 + bn + col];
    #pragma unroll
    for (int r = 0; r < 4; r++) {
      float a = aacc[nt][r] + ba;
      float gv = gacc[nt][r] + bg2;
      float gl = 0.5f * gv * (1.f + erff(gv * 0.70710678118654752f));
      Cs[(m0 + 4*g + r)*68 + col] = a * gl;
    }
  }
  __syncthreads();
  #pragma unroll
  for (int i = 0; i < 4; i++) {
    int p = t + i*256;
    int mm = p >> 5, nn = (p & 31)*2;
    *(unsigned*)&C[(size_t)(bm + mm)*1280 + bn + nn] = pack2(Cs[mm*68 + nn], Cs[mm*68 + nn + 1]);
  }
}

// ---------------- Self-attention partial: ones-row l-via-MFMA, reg-prefetch ----------------
__global__ __launch_bounds__(512) void self_attn_part(
    const u16* __restrict__ Q, const u16* __restrict__ K,
    const u16* __restrict__ vT, u16* __restrict__ Opart,
    float* __restrict__ Lp) {
  const int h = blockIdx.y;
  const int q0 = blockIdx.x * 128;
  const int sp = blockIdx.z;
  const int tid = threadIdx.x;
  const int w = tid >> 6, lane = tid & 63;
  const int l16 = lane & 15, g = lane >> 4;

  __shared__ __align__(16) u16 Kls[64][72];
  __shared__ __align__(16) u16 Vt[48][72];
  __shared__ __align__(16) u16 PsT[8][16][72];

  for (int e = tid; e < 64*12; e += 512) {
    int r = e / 12, c = e % 12;
    *(unsigned*)&Kls[r][40 + 2*c] = 0u;
  }
  if (tid < 256) {
    int r = 40 + (tid >> 5), c = tid & 31;
    *(unsigned*)&Vt[r][2*c] = (r == 40) ? 0x3F803F80u : 0u;
  }

  short8v Qb[2];
  {
    const u16* qrow = Q + (size_t)(q0 + w*16 + l16)*320 + h*40;
    Qb[0] = *(const short8v*)(qrow + g*8);
    short8v z = {};
    Qb[1] = (g == 0) ? *(const short8v*)(qrow + 32) : z;
  }

  const u16* Kbase = K + (size_t)(sp*1024)*320 + h*40;
  const u16* Vbase = vT + (size_t)(h*40)*4096 + sp*1024;

  const int ksl = (tid < 320) ? tid : 0;
  const int keyK = ksl / 5, chK = ksl - keyK*5;
  const u16* gK = Kbase + (size_t)keyK*320 + chK*8;
  u16* lK = &Kls[keyK][chK*8];
  const int vsl = (tid >= 192) ? (tid - 192) : 0;
  const int dV = vsl >> 3, chV = vsl & 7;
  const u16* gV = Vbase + (size_t)dV*4096 + chV*8;
  u16* lV = &Vt[dV][chV*8];

  const bool doK = (tid < 320), doV = (tid >= 192);

  short8v rK = {}, rV = {};
  if (doK) rK = *(const short8v*)gK;
  if (doV) rV = *(const short8v*)gV;
  gK += 64*320; gV += 64;

  float4v Of[3] = {};

  for (int it = 0; it < 16; ++it) {
    __syncthreads();
    if (doK) *(short8v*)lK = rK;
    if (doV) *(short8v*)lV = rV;
    __syncthreads();
    if (it < 15) {
      if (doK) rK = *(const short8v*)gK;
      if (doV) rV = *(const short8v*)gV;
      gK += 64*320; gV += 64;
    }

    float4v Sf[4];
    #pragma unroll
    for (int mt = 0; mt < 4; mt++) {
      short8v ka0 = *(const short8v*)&Kls[mt*16 + l16][g*8];
      short8v ka1 = *(const short8v*)&Kls[mt*16 + l16][32 + g*8];
      float4v s = {};
      s = __builtin_amdgcn_mfma_f32_16x16x32_bf16(ka0, Qb[0], s, 0, 0, 0);
      s = __builtin_amdgcn_mfma_f32_16x16x32_bf16(ka1, Qb[1], s, 0, 0, 0);
      Sf[mt] = s;
    }

    #pragma unroll
    for (int mt = 0; mt < 4; mt++)
      #pragma unroll
      for (int r = 0; r < 4; r++)
        Sf[mt][r] = exp2f(Sf[mt][r]);

    #pragma unroll
    for (int mt = 0; mt < 4; mt++) {
      uint2 pk;
      pk.x = pack2(Sf[mt][0], Sf[mt][1]);
      pk.y = pack2(Sf[mt][2], Sf[mt][3]);
      *(uint2*)&PsT[w][l16][mt*16 + 4*g] = pk;
    }
    asm volatile("s_waitcnt lgkmcnt(0)" ::: "memory");

    #pragma unroll
    for (int ks = 0; ks < 2; ks++) {
      short8v pb = *(const short8v*)&PsT[w][l16][ks*32 + g*8];
      #pragma unroll
      for (int mt = 0; mt < 3; mt++) {
        short8v va = *(const short8v*)&Vt[mt*16 + l16][ks*32 + g*8];
        Of[mt] = __builtin_amdgcn_mfma_f32_16x16x32_bf16(va, pb, Of[mt], 0, 0, 0);
      }
    }
  }

  const int q = q0 + w*16 + l16;
  u16* orow = Opart + (size_t)sp*4096*320 + (size_t)q*320 + h*40;
  #pragma unroll
  for (int mt = 0; mt < 3; mt++) {
    #pragma unroll
    for (int rp = 0; rp < 2; rp++) {
      int d = mt*16 + 4*g + rp*2;
      if (d < 40)
        *(unsigned*)&orow[d] = pack2(Of[mt][rp*2], Of[mt][rp*2+1]);
    }
  }
  if (g == 2)
    Lp[sp*32768 + q*8 + h] = Of[2][0];
}

// ---------------- merge 4 partials -> ao bf16 ----------------
__global__ __launch_bounds__(256) void attn_merge(
    const u16* __restrict__ Opart, const float* __restrict__ Lp,
    u16* __restrict__ O) {
  int gid = blockIdx.x*256 + threadIdx.x;   // < 4096*8*20
  int dp = gid % 20;
  int qh = gid / 20;
  int q = qh >> 3, h = qh & 7;
  float ls = Lp[qh] + Lp[32768 + qh] + Lp[2*32768 + qh] + Lp[3*32768 + qh];
  size_t base = (size_t)q*320 + h*40 + dp*2;
  const size_t HBu = 4096u*320u;
  float r0 = 0.f, r1 = 0.f;
  #pragma unroll
  for (int sp = 0; sp < 4; sp++) {
    unsigned u = *(const unsigned*)&Opart[sp*HBu + base];
    r0 += bfu2f((u16)(u & 0xffffu));
    r1 += bfu2f((u16)(u >> 16));
  }
  float inv = 1.f / ls;
  *(unsigned*)&O[base] = pack2(r0*inv, r1*inv);
}

// ---------------- Cross-attention: single-shot MFMA, 77 keys, max-free ----------------
__global__ __launch_bounds__(256) void cross_attn_mfma(
    const u16* __restrict__ Q, const u16* __restrict__ Kc,
    const u16* __restrict__ Vc, u16* __restrict__ O) {
  const int h = blockIdx.y;
  const int q0 = blockIdx.x * 64;
  const int tid = threadIdx.x;
  const int w = tid >> 6, lane = tid & 63;
  const int l16 = lane & 15, g = lane >> 4;

  __shared__ __align__(16) u16 Kls[80][72];
  __shared__ __align__(16) u16 Vt[48][104];
  __shared__ __align__(16) u16 PsT[4][16][104];

  for (int e = tid; e < 80*12; e += 256) {
    int r = e / 12, c = e % 12;
    *(unsigned*)&Kls[r][40 + 2*c] = 0u;
  }
  for (int e = tid; e < 48*52; e += 256) {
    int r = e / 52, c = e % 52;
    *(unsigned*)&Vt[r][2*c] = 0u;
  }
  {
    int r = lane >> 2, c4 = (lane & 3)*4;
    uint2 z; z.x = 0u; z.y = 0u;
    *(uint2*)&PsT[w][r][80 + c4] = z;
  }

  short8v Qb[2];
  {
    const u16* qrow = Q + (size_t)(q0 + w*16 + l16)*320 + h*40;
    Qb[0] = *(const short8v*)(qrow + g*8);
    short8v z = {};
    Qb[1] = (g == 0) ? *(const short8v*)(qrow + 32) : z;
  }

  for (int e = tid; e < 1600; e += 256) {
    int key = e / 20, dp = e % 20;
    unsigned val = 0u;
    if (key < 77) val = *(const unsigned*)&Kc[(size_t)key*320 + h*40 + dp*2];
    *(unsigned*)&Kls[key][dp*2] = val;
  }
  __syncthreads();
  for (int e = tid; e < 1600; e += 256) {
    int kp = e / 40, d = e % 40;
    unsigned u0 = (kp*2     < 77) ? (unsigned)Vc[(size_t)(kp*2    )*320 + h*40 + d] : 0u;
    unsigned u1 = (kp*2 + 1 < 77) ? (unsigned)Vc[(size_t)(kp*2 + 1)*320 + h*40 + d] : 0u;
    *(unsigned*)&Vt[d][kp*2] = u0 | (u1 << 16);
  }
  __syncthreads();

  float4v Sf[5];
  #pragma unroll
  for (int mt = 0; mt < 5; mt++) {
    short8v ka0 = *(const short8v*)&Kls[mt*16 + l16][g*8];
    short8v ka1 = *(const short8v*)&Kls[mt*16 + l16][32 + g*8];
    float4v s = {};
    s = __builtin_amdgcn_mfma_f32_16x16x32_bf16(ka0, Qb[0], s, 0, 0, 0);
    s = __builtin_amdgcn_mfma_f32_16x16x32_bf16(ka1, Qb[1], s, 0, 0, 0);
    Sf[mt] = s;
  }

  float rsum = 0.f;
  #pragma unroll
  for (int mt = 0; mt < 5; mt++)
    #pragma unroll
    for (int r = 0; r < 4; r++) {
      int key = mt*16 + 4*g + r;
      float p = (key < 77) ? exp2f(Sf[mt][r]) : 0.f;
      Sf[mt][r] = p; rsum += p;
    }
  rsum += __shfl_xor(rsum, 16);
  rsum += __shfl_xor(rsum, 32);

  #pragma unroll
  for (int mt = 0; mt < 5; mt++) {
    uint2 pk;
    pk.x = pack2(Sf[mt][0], Sf[mt][1]);
    pk.y = pack2(Sf[mt][2], Sf[mt][3]);
    *(uint2*)&PsT[w][l16][mt*16 + 4*g] = pk;
  }
  __syncthreads();

  float4v Of[3] = {};
  #pragma unroll
  for (int ks = 0; ks < 3; ks++) {
    short8v pb = *(const short8v*)&PsT[w][l16][ks*32 + g*8];
    #pragma unroll
    for (int mt = 0; mt < 3; mt++) {
      short8v va = *(const short8v*)&Vt[mt*16 + l16][ks*32 + g*8];
      Of[mt] = __builtin_amdgcn_mfma_f32_16x16x32_bf16(va, pb, Of[mt], 0, 0, 0);
    }
  }

  float inv = 1.f / rsum;
  u16* orow = O + (size_t)(q0 + w*16 + l16)*320 + h*40;
  #pragma unroll
  for (int mt = 0; mt < 3; mt++) {
    #pragma unroll
    for (int rp = 0; rp < 2; rp++) {
      int d = mt*16 + 4*g + rp*2;
      if (d < 40)
        *(unsigned*)&orow[d] = pack2(Of[mt][rp*2] * inv, Of[mt][rp*2+1] * inv);
    }
  }
}

extern "C" void kernel_launch(void* const* d_in, const int* in_sizes, int n_in,
                              void* d_out, int out_size, void* d_ws, size_t ws_size,
                              hipStream_t stream) {
  const float* x        = (const float*)d_in[0];
  const float* ctx      = (const float*)d_in[1];
  const float* gn_s     = (const float*)d_in[2];
  const float* gn_b     = (const float*)d_in[3];
  const float* w_pin    = (const float*)d_in[4];
  const float* b_pin    = (const float*)d_in[5];
  const float* ln1_s    = (const float*)d_in[6];
  const float* ln1_b    = (const float*)d_in[7];
  const float* wq1      = (const float*)d_in[8];
  const float* wk1      = (const float*)d_in[9];
  const float* wv1      = (const float*)d_in[10];
  const float* wo1      = (const float*)d_in[11];
  const float* bo1      = (const float*)d_in[12];
  const float* ln2_s    = (const float*)d_in[13];
  const float* ln2_b    = (const float*)d_in[14];
  const float* wq2      = (const float*)d_in[15];
  const float* wk2      = (const float*)d_in[16];
  const float* wv2      = (const float*)d_in[17];
  const float* wo2      = (const float*)d_in[18];
  const float* bo2      = (const float*)d_in[19];
  const float* ln3_s    = (const float*)d_in[20];
  const float* ln3_b    = (const float*)d_in[21];
  const float* w_ff1    = (const float*)d_in[22];
  const float* b_ff1    = (const float*)d_in[23];
  const float* w_ff2    = (const float*)d_in[24];
  const float* b_ff2    = (const float*)d_in[25];
  const float* w_pout   = (const float*)d_in[26];
  const float* b_pout   = (const float*)d_in[27];
  float* out = (float*)d_out;

  u16* ws = (u16*)d_ws;
  const size_t HB = 4096u*320u;
  u16* h   = ws;
  u16* hn  = ws + HB;
  u16* q   = ws + 2*HB;    // q,k contiguous (QKV fused epilogue)
  u16* k   = ws + 3*HB;
  u16* vT  = ws + 4*HB;    // V^T [320][4096]
  u16* ao  = ws + 5*HB;
  u16* gnT = k;
  u16* gg  = q;            // GEGLU out overlays q,k,vT,ao
  u16* wb  = ws + 6*HB;
  size_t o = 0;
  u16* ctxb   = wb + o; o += 59136;
  u16* wq1T   = wb + o; o += 102400;   // stacked: wq1T,wk1T,wv1T = [960][320]
  u16* wk1T   = wb + o; o += 102400;
  u16* wv1T   = wb + o; o += 102400;
  u16* wo1T   = wb + o; o += 102400;
  u16* wq2T   = wb + o; o += 102400;
  u16* wk2T   = wb + o; o += 245760;   // stacked: wk2T,wv2T = [640][768]
  u16* wv2T   = wb + o; o += 245760;
  u16* wo2T   = wb + o; o += 102400;
  u16* wff1T  = wb + o; o += 819200;
  u16* wff2T  = wb + o; o += 409600;
  u16* wpoutT = wb + o; o += 102400;
  u16* wpinT  = wb + o; o += 102400;
  u16* kc     = wb + o; o += 24640;    // kc,vc contiguous
  u16* vc     = wb + o; o += 24640;
  float* psum = (float*)(wb + o);      // 256 partial sums
  float* psq  = psum + 256;
  u16* OpartB = (u16*)(psq + 256);               // 4 x HB bf16 = 10.5 MB
  float* Lpart = (float*)(OpartB + 4*HB);        // 4 x 32768 fp32

  TPack tp;
  const float* srcs[12] = {wq1, wk1, wv1, wo1, wq2, wo2, w_pin, w_pout, wk2, wv2, w_ff1, w_ff2};
  u16* dsts[12]         = {wq1T, wk1T, wv1T, wo1T, wq2T, wo2T, wpinT, wpoutT, wk2T, wv2T, wff1T, wff2T};
  int Ks[12] = {320,320,320,320,320,320,320,320,768,768,320,1280};
  int Ns[12] = {320,320,320,320,320,320,320,320,320,320,2560,320};
  int off = 0;
  for (int i = 0; i < 12; i++) {
    tp.d[i].src = srcs[i]; tp.d[i].dst = dsts[i];
    tp.d[i].K = Ks[i]; tp.d[i].N = Ns[i];
    tp.d[i].off = off; tp.d[i].tx = Ns[i]/32;
    tp.d[i].sc = (i == 0 || i == 4) ? SCALE_L2E : 1.0f;   // wq1, wq2 pre-scaled
    off += (Ks[i]/32)*(Ns[i]/32);
  }

  dim3 blk(256), g128x10(128, 10);
  const u16* nres = nullptr;
  const float* nb = nullptr;

  // prep: weight tcvt (off) + ctx cvt (58) + gn partial stats (256)
  hipLaunchKernelGGL(prep_kernel, dim3(off + 58 + 256), blk, 0, stream,
                     tp, off, ctx, ctxb, x, psum, psq);
  // fused: gn apply+transpose (320 blocks) || kc/vc GEMM (20 blocks)
  hipLaunchKernelGGL(gn_kcvc, dim3(340), blk, 0, stream,
                     x, psum, psq, gn_s, gn_b, gnT, ctxb, wk2T, kc);
  hipLaunchKernelGGL((oneshot<0>), g128x10, blk, 0, stream, gnT, wpinT, b_pin, nres, nb, (void*)h, 320, 1);
  hipLaunchKernelGGL(layernorm_kernel, dim3(4096), dim3(64), 0, stream, h, ln1_s, ln1_b, hn);
  // fused QKV one-shot: grid (128,30); segs 0,1 -> q,k; seg 2 -> vT
  hipLaunchKernelGGL(qkv_oneshot, dim3(128, 30), blk, 0, stream, hn, wq1T, q, vT, (int)HB);
  hipLaunchKernelGGL(self_attn_part, dim3(32, 8, 4), dim3(512), 0, stream, q, k, vT, OpartB, Lpart);
  hipLaunchKernelGGL(attn_merge, dim3(2560), blk, 0, stream, OpartB, Lpart, ao);
  hipLaunchKernelGGL((oneshot<0>), g128x10, blk, 0, stream, ao, wo1T, bo1, h, nb, (void*)h, 320, 1);
  hipLaunchKernelGGL(layernorm_kernel, dim3(4096), dim3(64), 0, stream, h, ln2_s, ln2_b, hn);
  hipLaunchKernelGGL((oneshot<0>), g128x10, blk, 0, stream, hn, wq2T, nb, nres, nb, (void*)q, 320, 1);
  hipLaunchKernelGGL(cross_attn_mfma, dim3(64, 8), blk, 0, stream, q, kc, vc, ao);
  hipLaunchKernelGGL((oneshot<0>), g128x10, blk, 0, stream, ao, wo2T, bo2, h, nb, (void*)h, 320, 1);
  hipLaunchKernelGGL(layernorm_kernel, dim3(4096), dim3(64), 0, stream, h, ln3_s, ln3_b, hn);
  hipLaunchKernelGGL(geglu_mfma, dim3(128, 20), blk, 0, stream, hn, wff1T, b_ff1, gg);
  hipLaunchKernelGGL((oneshot<0>), g128x10, blk, 0, stream, gg, wff2T, b_ff2, h, nb, (void*)h, 1280, 4);
  hipLaunchKernelGGL((oneshot<2>), g128x10, blk, 0, stream, h, wpoutT, b_pout, nres, x, (void*)out, 320, 1);
}

// Round 20
// 283.878 us; speedup vs baseline: 1.0169x; 1.0086x over previous
//
#include <hip/hip_runtime.h>
#include <hip/hip_bf16.h>
#include <math.h>

#define SCALE_L2E  0.22811011265722836f   // (1/sqrt(40)) * log2(e)

typedef __attribute__((ext_vector_type(8))) short short8v;
typedef __attribute__((ext_vector_type(4))) float float4v;
typedef unsigned short u16;

__device__ __forceinline__ unsigned pack2(float a, float b) {
  float2 f; f.x = a; f.y = b;
  __hip_bfloat162 h = __float22bfloat162_rn(f);
  return *(unsigned*)&h;
}
__device__ __forceinline__ float bfu2f(u16 u) {
  return __uint_as_float(((unsigned)u) << 16);
}
__device__ __forceinline__ u16 f2bf(float x) {
  __hip_bfloat16 h = __float2bfloat16(x);
  return *(u16*)&h;
}
// raw v_exp_f32 (D = 2^S0): skips __ocml_exp2_f32's range/denormal guards
// (safe: scores bounded +-~30 in exp2 units)
__device__ __forceinline__ float fexp2(float x) {
  float r;
  asm("v_exp_f32 %0, %1" : "=v"(r) : "v"(x));
  return r;
}

// ---------------- prep: weight transpose+convert | ctx cvt | gn PARTIAL stats --------------
struct TDesc { const float* src; u16* dst; int K, N, off, tx; float sc; };
struct TPack { TDesc d[12]; };

__global__ __launch_bounds__(256) void prep_kernel(
    TPack p, int nT,
    const float* __restrict__ ctxsrc, u16* __restrict__ ctxdst,
    const float* __restrict__ x,
    float* __restrict__ psum, float* __restrict__ psq) {
  __shared__ float ls[32][33];
  int bt = blockIdx.x, t = threadIdx.x;
  if (bt < nT) {
    int ti = 0;
    #pragma unroll
    for (int i = 1; i < 12; i++) if (bt >= p.d[i].off) ti = i;
    TDesc dd = p.d[ti];
    int local = bt - dd.off;
    int n0 = (local % dd.tx) * 32, k0 = (local / dd.tx) * 32;
    #pragma unroll
    for (int i = 0; i < 4; i++) {
      int idx = t + i*256, r = idx >> 5, c = idx & 31;
      ls[r][c] = dd.src[(size_t)(k0 + r)*dd.N + n0 + c];
    }
    __syncthreads();
    #pragma unroll
    for (int i = 0; i < 2; i++) {
      int p2 = t + i*256, n = p2 >> 4, kp = (p2 & 15)*2;
      *(unsigned*)&dd.dst[(size_t)(n0 + n)*dd.K + k0 + kp] =
        pack2(ls[kp][n]*dd.sc, ls[kp+1][n]*dd.sc);
    }
  } else if (bt < nT + 58) {
    int idx = ((bt - nT)*256 + t)*4;
    if (idx < 59136) {
      float4 v = *(const float4*)&ctxsrc[idx];
      uint2 o; o.x = pack2(v.x, v.y); o.y = pack2(v.z, v.w);
      *(uint2*)&ctxdst[idx] = o;
    }
  } else {
    int pp = bt - nT - 58;            // 0..255
    int g = pp >> 3, part = pp & 7;
    size_t base = (size_t)g*40960 + (size_t)part*5120;
    float sum = 0.f, sq = 0.f;
    #pragma unroll
    for (int r = 0; r < 5; r++) {
      float4 v = *(const float4*)&x[base + (size_t)(t + r*256)*4];
      sum += v.x + v.y + v.z + v.w;
      sq  += v.x*v.x + v.y*v.y + v.z*v.z + v.w*v.w;
    }
    float* s1 = &ls[0][0];
    float* s2 = &ls[8][0] + 8;
    s1[t] = sum; s2[t] = sq; __syncthreads();
    for (int st = 128; st > 0; st >>= 1) {
      if (t < st) { s1[t] += s1[t+st]; s2[t] += s2[t+st]; }
      __syncthreads();
    }
    if (t == 0) { psum[pp] = s1[0]; psq[pp] = s2[0]; }
  }
}

// ---------------- fused: GN apply+transpose (blocks 0..319) | kc/vc GEMM (320..339) --------
__global__ __launch_bounds__(256) void gn_kcvc(
    const float* __restrict__ x, const float* __restrict__ psum,
    const float* __restrict__ psq, const float* __restrict__ gs,
    const float* __restrict__ gb, u16* __restrict__ gnT,
    const u16* __restrict__ ctxb, const u16* __restrict__ wk2T,
    u16* __restrict__ kcvc) {
  __shared__ __align__(16) u16 smem[2*64*72];
  __shared__ float scl[64], sft[64];
  const int t = threadIdx.x;
  if (blockIdx.x < 320) {
    float* ts = (float*)smem;
    int s0 = (blockIdx.x & 63) * 64, c0 = (blockIdx.x >> 6) * 64;
    if (t < 64) {
      int c = c0 + t, g = c / 10;
      float s = 0.f, q = 0.f;
      #pragma unroll
      for (int i = 0; i < 8; i++) { s += psum[g*8 + i]; q += psq[g*8 + i]; }
      float mu = s * (1.f/40960.f);
      float var = q * (1.f/40960.f) - mu*mu;
      float rs = rsqrtf(var + 1e-6f);
      float sc = rs * gs[c];
      scl[t] = sc;
      sft[t] = gb[c] - mu * sc;
    }
    int crow = t >> 2, sch = (t & 3) * 16;
    #pragma unroll
    for (int j = 0; j < 4; j++) {
      float4 v = *(const float4*)&x[(size_t)(c0 + crow)*4096 + s0 + sch + 4*j];
      ts[crow*65 + sch + 4*j + 0] = v.x; ts[crow*65 + sch + 4*j + 1] = v.y;
      ts[crow*65 + sch + 4*j + 2] = v.z; ts[crow*65 + sch + 4*j + 3] = v.w;
    }
    __syncthreads();
    int srow = t >> 2, cch = (t & 3) * 16;
    #pragma unroll
    for (int p = 0; p < 8; p++) {
      int cl = cch + 2*p;
      float f0 = ts[cl*65 + srow] * scl[cl] + sft[cl];
      float f1 = ts[(cl+1)*65 + srow] * scl[cl+1] + sft[cl+1];
      *(unsigned*)&gnT[(size_t)(s0 + srow)*320 + c0 + cl] = pack2(f0, f1);
    }
  } else {
    u16* As = smem;
    u16* Bs = smem + 64*72;
    const int lane = t & 63, w = t >> 6, l16 = lane & 15, g = lane >> 4;
    int local = blockIdx.x - 320;
    const int bm = (local & 1) * 64, bn = (local >> 1) * 64;
    const int m0 = (w & 1) * 32, n0 = (w >> 1) * 32;
    float4v acc[2][2] = {};
    const int ar = t >> 2, ac = (t & 3) * 16;
    const bool aok = (bm + ar) < 77;
    const u16* ga = &ctxb[(size_t)(bm + ar)*768 + ac];
    const u16* gbp = &wk2T[(size_t)(bn + ar)*768 + ac];
    short8v pa0 = {}, pa1 = {}, pb0, pb1;
    if (aok) { pa0 = *(const short8v*)ga; pa1 = *(const short8v*)(ga + 8); }
    pb0 = *(const short8v*)gbp; pb1 = *(const short8v*)(gbp + 8);
    for (int k0 = 0; k0 < 768; k0 += 64) {
      __syncthreads();
      *(short8v*)&As[ar*72 + ac] = pa0;
      *(short8v*)&As[ar*72 + ac + 8] = pa1;
      *(short8v*)&Bs[ar*72 + ac] = pb0;
      *(short8v*)&Bs[ar*72 + ac + 8] = pb1;
      __syncthreads();
      if (k0 + 64 < 768) {
        if (aok) { pa0 = *(const short8v*)(ga + k0 + 64); pa1 = *(const short8v*)(ga + k0 + 72); }
        pb0 = *(const short8v*)(gbp + k0 + 64); pb1 = *(const short8v*)(gbp + k0 + 72);
      }
      #pragma unroll
      for (int ks = 0; ks < 2; ks++) {
        short8v af[2], bfv[2];
        #pragma unroll
        for (int mt = 0; mt < 2; mt++)
          af[mt] = *(const short8v*)&As[(m0 + 16*mt + l16)*72 + ks*32 + g*8];
        #pragma unroll
        for (int nt = 0; nt < 2; nt++)
          bfv[nt] = *(const short8v*)&Bs[(n0 + 16*nt + l16)*72 + ks*32 + g*8];
        #pragma unroll
        for (int mt = 0; mt < 2; mt++)
          #pragma unroll
          for (int nt = 0; nt < 2; nt++)
            acc[mt][nt] = __builtin_amdgcn_mfma_f32_16x16x32_bf16(af[mt], bfv[nt], acc[mt][nt], 0, 0, 0);
      }
    }
    __syncthreads();
    float* Cs = (float*)smem;
    #pragma unroll
    for (int mt = 0; mt < 2; mt++)
      #pragma unroll
      for (int nt = 0; nt < 2; nt++)
        #pragma unroll
        for (int r = 0; r < 4; r++)
          Cs[(m0 + 16*mt + 4*g + r)*68 + n0 + 16*nt + l16] = acc[mt][nt][r];
    __syncthreads();
    u16* C = kcvc + (size_t)(bn / 320) * 24640;
    int nb = bn % 320;
    #pragma unroll
    for (int i = 0; i < 8; i++) {
      int p = t + i*256;
      int mm = p >> 5, nn = (p & 31)*2;
      if (bm + mm >= 77) continue;
      *(unsigned*)&C[(size_t)(bm + mm)*320 + nb + nn] = pack2(Cs[mm*68 + nn], Cs[mm*68 + nn + 1]);
    }
  }
}

// ---------------- LayerNorm bf16->bf16: one wave per row of 320 ----------------
__global__ __launch_bounds__(64) void layernorm_kernel(
    const u16* __restrict__ X, const float* __restrict__ s,
    const float* __restrict__ b, u16* __restrict__ Y) {
  int row = blockIdx.x, t = threadIdx.x;
  const u16* xr = X + (size_t)row*320;
  float v[5], sum = 0.f, sq = 0.f;
  #pragma unroll
  for (int i = 0; i < 5; i++) { v[i] = bfu2f(xr[t + 64*i]); sum += v[i]; sq += v[i]*v[i]; }
  #pragma unroll
  for (int o = 32; o > 0; o >>= 1) { sum += __shfl_down(sum, o); sq += __shfl_down(sq, o); }
  sum = __shfl(sum, 0); sq = __shfl(sq, 0);
  float mu = sum * (1.f/320.f);
  float var = sq * (1.f/320.f) - mu*mu;
  float rs = rsqrtf(var + 1e-5f);
  u16* yr = Y + (size_t)row*320;
  #pragma unroll
  for (int i = 0; i < 5; i++) {
    int c = t + 64*i;
    yr[c] = f2bf((v[i]-mu)*rs*s[c] + b[c]);
  }
}

// ---------------- One-shot GEMM (BM=32): C[M,320] = A[M,K] * BT[320,K]^T -----------------
template<int MODE>
__global__ __launch_bounds__(256) void oneshot(
    const u16* __restrict__ A, const u16* __restrict__ BT,
    const float* __restrict__ bias, const u16* __restrict__ res,
    const float* __restrict__ xres, void* __restrict__ Cout,
    int K, int chunks) {
  __shared__ __align__(16) u16 As[32*328];
  __shared__ __align__(16) u16 Bs[32*328];
  const int t = threadIdx.x;
  const int lane = t & 63, w = t >> 6, l16 = lane & 15, g = lane >> 4;
  const int bm = blockIdx.x * 32, bn = blockIdx.y * 32;
  const int m0 = (w & 1) * 16, n0 = (w >> 1) * 16;
  float4v acc = {};

  const u16* Ab = A + (size_t)(bm + (t>>3))*K + (t&7)*16;
  u16* Al = As + (t>>3)*328 + (t&7)*16;
  const u16* Bb = BT + (size_t)(bn + (t>>3))*K + (t&7)*16;
  u16* Bl = Bs + (t>>3)*328 + (t&7)*16;
  const bool b3 = (t & 7) < 4;

  for (int ch = 0; ch < chunks; ch++) {
    const int c0 = ch*320;
    __syncthreads();
    *(short8v*)Al         = *(const short8v*)(Ab + c0);
    *(short8v*)(Al + 8)   = *(const short8v*)(Ab + c0 + 8);
    *(short8v*)(Al + 128) = *(const short8v*)(Ab + c0 + 128);
    *(short8v*)(Al + 136) = *(const short8v*)(Ab + c0 + 136);
    *(short8v*)Bl         = *(const short8v*)(Bb + c0);
    *(short8v*)(Bl + 8)   = *(const short8v*)(Bb + c0 + 8);
    *(short8v*)(Bl + 128) = *(const short8v*)(Bb + c0 + 128);
    *(short8v*)(Bl + 136) = *(const short8v*)(Bb + c0 + 136);
    if (b3) {
      *(short8v*)(Al + 256) = *(const short8v*)(Ab + c0 + 256);
      *(short8v*)(Al + 264) = *(const short8v*)(Ab + c0 + 264);
      *(short8v*)(Bl + 256) = *(const short8v*)(Bb + c0 + 256);
      *(short8v*)(Bl + 264) = *(const short8v*)(Bb + c0 + 264);
    }
    __syncthreads();
    #pragma unroll
    for (int ks = 0; ks < 10; ks++) {
      short8v bfv = *(const short8v*)&Bs[(n0 + l16)*328 + ks*32 + g*8];
      short8v af  = *(const short8v*)&As[(m0 + l16)*328 + ks*32 + g*8];
      acc = __builtin_amdgcn_mfma_f32_16x16x32_bf16(af, bfv, acc, 0, 0, 0);
    }
  }
  __syncthreads();
  float* Cs = (float*)As;   // [32][36]
  #pragma unroll
  for (int r = 0; r < 4; r++)
    Cs[(m0 + 4*g + r)*36 + n0 + l16] = acc[r];
  __syncthreads();

  if (MODE == 0) {
    u16* C = (u16*)Cout;
    #pragma unroll
    for (int i = 0; i < 2; i++) {
      int p = t + i*256;
      int mm = p >> 4, pp = (p & 15)*2;
      float f0 = Cs[mm*36 + pp], f1 = Cs[mm*36 + pp + 1];
      if (bias) { f0 += bias[bn + pp]; f1 += bias[bn + pp + 1]; }
      if (res) {
        unsigned u = *(const unsigned*)&res[(size_t)(bm + mm)*320 + bn + pp];
        f0 += bfu2f((u16)(u & 0xffffu));
        f1 += bfu2f((u16)(u >> 16));
      }
      *(unsigned*)&C[(size_t)(bm + mm)*320 + bn + pp] = pack2(f0, f1);
    }
  } else {
    float* C = (float*)Cout;
    int nloc = t >> 3, mch = (t & 7) * 4;
    float bb = bias[bn + nloc];
    float4 xv = *(const float4*)&xres[(size_t)(bn + nloc)*4096 + bm + mch];
    float4 ov;
    ov.x = Cs[(mch+0)*36 + nloc] + bb + xv.x;
    ov.y = Cs[(mch+1)*36 + nloc] + bb + xv.y;
    ov.z = Cs[(mch+2)*36 + nloc] + bb + xv.z;
    ov.w = Cs[(mch+3)*36 + nloc] + bb + xv.w;
    *(float4*)&C[(size_t)(bn + nloc)*4096 + bm + mch] = ov;
  }
}

// ---------------- QKV one-shot (BM=32): grid (128, 30) ----------
__global__ __launch_bounds__(256) void qkv_oneshot(
    const u16* __restrict__ A, const u16* __restrict__ BT,
    u16* __restrict__ qk, u16* __restrict__ vT, int segStride) {
  __shared__ __align__(16) u16 As[32*328];
  __shared__ __align__(16) u16 Bs[32*328];
  const int t = threadIdx.x;
  const int lane = t & 63, w = t >> 6, l16 = lane & 15, g = lane >> 4;
  const int bm = blockIdx.x * 32, bn = blockIdx.y * 32;
  const int m0 = (w & 1) * 16, n0 = (w >> 1) * 16;
  float4v acc = {};

  const u16* Ab = A + (size_t)(bm + (t>>3))*320 + (t&7)*16;
  u16* Al = As + (t>>3)*328 + (t&7)*16;
  const u16* Bb = BT + (size_t)(bn + (t>>3))*320 + (t&7)*16;
  u16* Bl = Bs + (t>>3)*328 + (t&7)*16;
  const bool b3 = (t & 7) < 4;

  *(short8v*)Al         = *(const short8v*)Ab;
  *(short8v*)(Al + 8)   = *(const short8v*)(Ab + 8);
  *(short8v*)(Al + 128) = *(const short8v*)(Ab + 128);
  *(short8v*)(Al + 136) = *(const short8v*)(Ab + 136);
  *(short8v*)Bl         = *(const short8v*)Bb;
  *(short8v*)(Bl + 8)   = *(const short8v*)(Bb + 8);
  *(short8v*)(Bl + 128) = *(const short8v*)(Bb + 128);
  *(short8v*)(Bl + 136) = *(const short8v*)(Bb + 136);
  if (b3) {
    *(short8v*)(Al + 256) = *(const short8v*)(Ab + 256);
    *(short8v*)(Al + 264) = *(const short8v*)(Ab + 264);
    *(short8v*)(Bl + 256) = *(const short8v*)(Bb + 256);
    *(short8v*)(Bl + 264) = *(const short8v*)(Bb + 264);
  }
  __syncthreads();
  #pragma unroll
  for (int ks = 0; ks < 10; ks++) {
    short8v bfv = *(const short8v*)&Bs[(n0 + l16)*328 + ks*32 + g*8];
    short8v af  = *(const short8v*)&As[(m0 + l16)*328 + ks*32 + g*8];
    acc = __builtin_amdgcn_mfma_f32_16x16x32_bf16(af, bfv, acc, 0, 0, 0);
  }
  __syncthreads();
  float* Cs = (float*)As;   // [32][36]
  #pragma unroll
  for (int r = 0; r < 4; r++)
    Cs[(m0 + 4*g + r)*36 + n0 + l16] = acc[r];
  __syncthreads();

  if (bn < 640) {
    u16* C = qk + (size_t)(bn / 320) * segStride;
    int nb = bn % 320;
    #pragma unroll
    for (int i = 0; i < 2; i++) {
      int p = t + i*256;
      int mm = p >> 4, pp = (p & 15)*2;
      *(unsigned*)&C[(size_t)(bm + mm)*320 + nb + pp] = pack2(Cs[mm*36 + pp], Cs[mm*36 + pp + 1]);
    }
  } else {
    int nloc = t >> 3, mch = (t & 7) * 4;
    int vd = bn - 640 + nloc;
    u16* dst = vT + (size_t)vd*4096 + bm + mch;
    uint2 o0;
    o0.x = pack2(Cs[(mch+0)*36 + nloc], Cs[(mch+1)*36 + nloc]);
    o0.y = pack2(Cs[(mch+2)*36 + nloc], Cs[(mch+3)*36 + nloc]);
    *(uint2*)dst = o0;
  }
}

// ---------------- GEGLU MFMA (BM=32, reg-prefetch): grid (128, 20) ----------------
__global__ __launch_bounds__(256) void geglu_mfma(
    const u16* __restrict__ A, const u16* __restrict__ BT,
    const float* __restrict__ bias, u16* __restrict__ C) {
  __shared__ __align__(16) u16 smem[32*72 + 2*64*72];
  u16* As = smem;
  u16* Ba = smem + 32*72;
  u16* Bg = smem + 32*72 + 64*72;
  const int t = threadIdx.x;
  const int lane = t & 63, w = t >> 6, l16 = lane & 15, g = lane >> 4;
  const int bm = blockIdx.x * 32, bn = blockIdx.y * 64;
  const int m0 = (w & 1) * 16, n0 = (w >> 1) * 32;
  float4v aacc[2] = {}, gacc[2] = {};
  const int arA = t >> 3, acA = (t & 7) * 8;
  const int arB = t >> 2, acB = (t & 3) * 16;
  const u16* ga  = &A[(size_t)(bm + arA)*320 + acA];
  const u16* gba = &BT[(size_t)(bn + arB)*320 + acB];
  const u16* gbg = &BT[(size_t)(1280 + bn + arB)*320 + acB];

  short8v pa0 = *(const short8v*)ga;
  short8v pb0 = *(const short8v*)gba, pb1 = *(const short8v*)(gba + 8);
  short8v pg0 = *(const short8v*)gbg, pg1 = *(const short8v*)(gbg + 8);

  for (int k0 = 0; k0 < 320; k0 += 64) {
    __syncthreads();
    *(short8v*)&As[arA*72 + acA] = pa0;
    *(short8v*)&Ba[arB*72 + acB] = pb0;
    *(short8v*)&Ba[arB*72 + acB + 8] = pb1;
    *(short8v*)&Bg[arB*72 + acB] = pg0;
    *(short8v*)&Bg[arB*72 + acB + 8] = pg1;
    __syncthreads();
    if (k0 + 64 < 320) {
      pa0 = *(const short8v*)(ga + k0 + 64);
      pb0 = *(const short8v*)(gba + k0 + 64); pb1 = *(const short8v*)(gba + k0 + 72);
      pg0 = *(const short8v*)(gbg + k0 + 64); pg1 = *(const short8v*)(gbg + k0 + 72);
    }
    #pragma unroll
    for (int ks = 0; ks < 2; ks++) {
      short8v af = *(const short8v*)&As[(m0 + l16)*72 + ks*32 + g*8];
      #pragma unroll
      for (int nt = 0; nt < 2; nt++) {
        short8v bav = *(const short8v*)&Ba[(n0 + 16*nt + l16)*72 + ks*32 + g*8];
        short8v bgv = *(const short8v*)&Bg[(n0 + 16*nt + l16)*72 + ks*32 + g*8];
        aacc[nt] = __builtin_amdgcn_mfma_f32_16x16x32_bf16(af, bav, aacc[nt], 0, 0, 0);
        gacc[nt] = __builtin_amdgcn_mfma_f32_16x16x32_bf16(af, bgv, gacc[nt], 0, 0, 0);
      }
    }
  }
  __syncthreads();
  float* Cs = (float*)smem;   // [32][68]
  #pragma unroll
  for (int nt = 0; nt < 2; nt++) {
    int col = n0 + 16*nt + l16;
    float ba = bias[bn + col];
    float bg2 = bias[1280 + bn + col];
    #pragma unroll
    for (int r = 0; r < 4; r++) {
      float a = aacc[nt][r] + ba;
      float gv = gacc[nt][r] + bg2;
      float gl = 0.5f * gv * (1.f + erff(gv * 0.70710678118654752f));
      Cs[(m0 + 4*g + r)*68 + col] = a * gl;
    }
  }
  __syncthreads();
  #pragma unroll
  for (int i = 0; i < 4; i++) {
    int p = t + i*256;
    int mm = p >> 5, nn = (p & 31)*2;
    *(unsigned*)&C[(size_t)(bm + mm)*1280 + bn + nn] = pack2(Cs[mm*68 + nn], Cs[mm*68 + nn + 1]);
  }
}

// ---------------- Self-attention partial: ones-row l-via-MFMA, reg-prefetch, raw v_exp ----
__global__ __launch_bounds__(512) void self_attn_part(
    const u16* __restrict__ Q, const u16* __restrict__ K,
    const u16* __restrict__ vT, u16* __restrict__ Opart,
    float* __restrict__ Lp) {
  const int h = blockIdx.y;
  const int q0 = blockIdx.x * 128;
  const int sp = blockIdx.z;
  const int tid = threadIdx.x;
  const int w = tid >> 6, lane = tid & 63;
  const int l16 = lane & 15, g = lane >> 4;

  __shared__ __align__(16) u16 Kls[64][72];
  __shared__ __align__(16) u16 Vt[48][72];
  __shared__ __align__(16) u16 PsT[8][16][72];

  for (int e = tid; e < 64*12; e += 512) {
    int r = e / 12, c = e % 12;
    *(unsigned*)&Kls[r][40 + 2*c] = 0u;
  }
  if (tid < 256) {
    int r = 40 + (tid >> 5), c = tid & 31;
    *(unsigned*)&Vt[r][2*c] = (r == 40) ? 0x3F803F80u : 0u;
  }

  short8v Qb[2];
  {
    const u16* qrow = Q + (size_t)(q0 + w*16 + l16)*320 + h*40;
    Qb[0] = *(const short8v*)(qrow + g*8);
    short8v z = {};
    Qb[1] = (g == 0) ? *(const short8v*)(qrow + 32) : z;
  }

  const u16* Kbase = K + (size_t)(sp*1024)*320 + h*40;
  const u16* Vbase = vT + (size_t)(h*40)*4096 + sp*1024;

  const int ksl = (tid < 320) ? tid : 0;
  const int keyK = ksl / 5, chK = ksl - keyK*5;
  const u16* gK = Kbase + (size_t)keyK*320 + chK*8;
  u16* lK = &Kls[keyK][chK*8];
  const int vsl = (tid >= 192) ? (tid - 192) : 0;
  const int dV = vsl >> 3, chV = vsl & 7;
  const u16* gV = Vbase + (size_t)dV*4096 + chV*8;
  u16* lV = &Vt[dV][chV*8];

  const bool doK = (tid < 320), doV = (tid >= 192);

  short8v rK = {}, rV = {};
  if (doK) rK = *(const short8v*)gK;
  if (doV) rV = *(const short8v*)gV;
  gK += 64*320; gV += 64;

  float4v Of[3] = {};

  for (int it = 0; it < 16; ++it) {
    __syncthreads();
    if (doK) *(short8v*)lK = rK;
    if (doV) *(short8v*)lV = rV;
    __syncthreads();
    if (it < 15) {
      if (doK) rK = *(const short8v*)gK;
      if (doV) rV = *(const short8v*)gV;
      gK += 64*320; gV += 64;
    }

    float4v Sf[4];
    #pragma unroll
    for (int mt = 0; mt < 4; mt++) {
      short8v ka0 = *(const short8v*)&Kls[mt*16 + l16][g*8];
      short8v ka1 = *(const short8v*)&Kls[mt*16 + l16][32 + g*8];
      float4v s = {};
      s = __builtin_amdgcn_mfma_f32_16x16x32_bf16(ka0, Qb[0], s, 0, 0, 0);
      s = __builtin_amdgcn_mfma_f32_16x16x32_bf16(ka1, Qb[1], s, 0, 0, 0);
      Sf[mt] = s;
    }

    #pragma unroll
    for (int mt = 0; mt < 4; mt++)
      #pragma unroll
      for (int r = 0; r < 4; r++)
        Sf[mt][r] = fexp2(Sf[mt][r]);

    #pragma unroll
    for (int mt = 0; mt < 4; mt++) {
      uint2 pk;
      pk.x = pack2(Sf[mt][0], Sf[mt][1]);
      pk.y = pack2(Sf[mt][2], Sf[mt][3]);
      *(uint2*)&PsT[w][l16][mt*16 + 4*g] = pk;
    }
    asm volatile("s_waitcnt lgkmcnt(0)" ::: "memory");

    #pragma unroll
    for (int ks = 0; ks < 2; ks++) {
      short8v pb = *(const short8v*)&PsT[w][l16][ks*32 + g*8];
      #pragma unroll
      for (int mt = 0; mt < 3; mt++) {
        short8v va = *(const short8v*)&Vt[mt*16 + l16][ks*32 + g*8];
        Of[mt] = __builtin_amdgcn_mfma_f32_16x16x32_bf16(va, pb, Of[mt], 0, 0, 0);
      }
    }
  }

  const int q = q0 + w*16 + l16;
  u16* orow = Opart + (size_t)sp*4096*320 + (size_t)q*320 + h*40;
  #pragma unroll
  for (int mt = 0; mt < 3; mt++) {
    #pragma unroll
    for (int rp = 0; rp < 2; rp++) {
      int d = mt*16 + 4*g + rp*2;
      if (d < 40)
        *(unsigned*)&orow[d] = pack2(Of[mt][rp*2], Of[mt][rp*2+1]);
    }
  }
  if (g == 2)
    Lp[sp*32768 + q*8 + h] = Of[2][0];
}

// ---------------- merge 4 partials -> ao bf16 ----------------
__global__ __launch_bounds__(256) void attn_merge(
    const u16* __restrict__ Opart, const float* __restrict__ Lp,
    u16* __restrict__ O) {
  int gid = blockIdx.x*256 + threadIdx.x;   // < 4096*8*20
  int dp = gid % 20;
  int qh = gid / 20;
  int q = qh >> 3, h = qh & 7;
  float ls = Lp[qh] + Lp[32768 + qh] + Lp[2*32768 + qh] + Lp[3*32768 + qh];
  size_t base = (size_t)q*320 + h*40 + dp*2;
  const size_t HBu = 4096u*320u;
  float r0 = 0.f, r1 = 0.f;
  #pragma unroll
  for (int sp = 0; sp < 4; sp++) {
    unsigned u = *(const unsigned*)&Opart[sp*HBu + base];
    r0 += bfu2f((u16)(u & 0xffffu));
    r1 += bfu2f((u16)(u >> 16));
  }
  float inv = 1.f / ls;
  *(unsigned*)&O[base] = pack2(r0*inv, r1*inv);
}

// ---------------- Cross-attention: single-shot MFMA, 77 keys, max-free, raw v_exp ---------
__global__ __launch_bounds__(256) void cross_attn_mfma(
    const u16* __restrict__ Q, const u16* __restrict__ Kc,
    const u16* __restrict__ Vc, u16* __restrict__ O) {
  const int h = blockIdx.y;
  const int q0 = blockIdx.x * 64;
  const int tid = threadIdx.x;
  const int w = tid >> 6, lane = tid & 63;
  const int l16 = lane & 15, g = lane >> 4;

  __shared__ __align__(16) u16 Kls[80][72];
  __shared__ __align__(16) u16 Vt[48][104];
  __shared__ __align__(16) u16 PsT[4][16][104];

  for (int e = tid; e < 80*12; e += 256) {
    int r = e / 12, c = e % 12;
    *(unsigned*)&Kls[r][40 + 2*c] = 0u;
  }
  for (int e = tid; e < 48*52; e += 256) {
    int r = e / 52, c = e % 52;
    *(unsigned*)&Vt[r][2*c] = 0u;
  }
  {
    int r = lane >> 2, c4 = (lane & 3)*4;
    uint2 z; z.x = 0u; z.y = 0u;
    *(uint2*)&PsT[w][r][80 + c4] = z;
  }

  short8v Qb[2];
  {
    const u16* qrow = Q + (size_t)(q0 + w*16 + l16)*320 + h*40;
    Qb[0] = *(const short8v*)(qrow + g*8);
    short8v z = {};
    Qb[1] = (g == 0) ? *(const short8v*)(qrow + 32) : z;
  }

  for (int e = tid; e < 1600; e += 256) {
    int key = e / 20, dp = e % 20;
    unsigned val = 0u;
    if (key < 77) val = *(const unsigned*)&Kc[(size_t)key*320 + h*40 + dp*2];
    *(unsigned*)&Kls[key][dp*2] = val;
  }
  __syncthreads();
  for (int e = tid; e < 1600; e += 256) {
    int kp = e / 40, d = e % 40;
    unsigned u0 = (kp*2     < 77) ? (unsigned)Vc[(size_t)(kp*2    )*320 + h*40 + d] : 0u;
    unsigned u1 = (kp*2 + 1 < 77) ? (unsigned)Vc[(size_t)(kp*2 + 1)*320 + h*40 + d] : 0u;
    *(unsigned*)&Vt[d][kp*2] = u0 | (u1 << 16);
  }
  __syncthreads();

  float4v Sf[5];
  #pragma unroll
  for (int mt = 0; mt < 5; mt++) {
    short8v ka0 = *(const short8v*)&Kls[mt*16 + l16][g*8];
    short8v ka1 = *(const short8v*)&Kls[mt*16 + l16][32 + g*8];
    float4v s = {};
    s = __builtin_amdgcn_mfma_f32_16x16x32_bf16(ka0, Qb[0], s, 0, 0, 0);
    s = __builtin_amdgcn_mfma_f32_16x16x32_bf16(ka1, Qb[1], s, 0, 0, 0);
    Sf[mt] = s;
  }

  float rsum = 0.f;
  #pragma unroll
  for (int mt = 0; mt < 5; mt++)
    #pragma unroll
    for (int r = 0; r < 4; r++) {
      int key = mt*16 + 4*g + r;
      float p = (key < 77) ? fexp2(Sf[mt][r]) : 0.f;
      Sf[mt][r] = p; rsum += p;
    }
  rsum += __shfl_xor(rsum, 16);
  rsum += __shfl_xor(rsum, 32);

  #pragma unroll
  for (int mt = 0; mt < 5; mt++) {
    uint2 pk;
    pk.x = pack2(Sf[mt][0], Sf[mt][1]);
    pk.y = pack2(Sf[mt][2], Sf[mt][3]);
    *(uint2*)&PsT[w][l16][mt*16 + 4*g] = pk;
  }
  __syncthreads();

  float4v Of[3] = {};
  #pragma unroll
  for (int ks = 0; ks < 3; ks++) {
    short8v pb = *(const short8v*)&PsT[w][l16][ks*32 + g*8];
    #pragma unroll
    for (int mt = 0; mt < 3; mt++) {
      short8v va = *(const short8v*)&Vt[mt*16 + l16][ks*32 + g*8];
      Of[mt] = __builtin_amdgcn_mfma_f32_16x16x32_bf16(va, pb, Of[mt], 0, 0, 0);
    }
  }

  float inv = 1.f / rsum;
  u16* orow = O + (size_t)(q0 + w*16 + l16)*320 + h*40;
  #pragma unroll
  for (int mt = 0; mt < 3; mt++) {
    #pragma unroll
    for (int rp = 0; rp < 2; rp++) {
      int d = mt*16 + 4*g + rp*2;
      if (d < 40)
        *(unsigned*)&orow[d] = pack2(Of[mt][rp*2] * inv, Of[mt][rp*2+1] * inv);
    }
  }
}

extern "C" void kernel_launch(void* const* d_in, const int* in_sizes, int n_in,
                              void* d_out, int out_size, void* d_ws, size_t ws_size,
                              hipStream_t stream) {
  const float* x        = (const float*)d_in[0];
  const float* ctx      = (const float*)d_in[1];
  const float* gn_s     = (const float*)d_in[2];
  const float* gn_b     = (const float*)d_in[3];
  const float* w_pin    = (const float*)d_in[4];
  const float* b_pin    = (const float*)d_in[5];
  const float* ln1_s    = (const float*)d_in[6];
  const float* ln1_b    = (const float*)d_in[7];
  const float* wq1      = (const float*)d_in[8];
  const float* wk1      = (const float*)d_in[9];
  const float* wv1      = (const float*)d_in[10];
  const float* wo1      = (const float*)d_in[11];
  const float* bo1      = (const float*)d_in[12];
  const float* ln2_s    = (const float*)d_in[13];
  const float* ln2_b    = (const float*)d_in[14];
  const float* wq2      = (const float*)d_in[15];
  const float* wk2      = (const float*)d_in[16];
  const float* wv2      = (const float*)d_in[17];
  const float* wo2      = (const float*)d_in[18];
  const float* bo2      = (const float*)d_in[19];
  const float* ln3_s    = (const float*)d_in[20];
  const float* ln3_b    = (const float*)d_in[21];
  const float* w_ff1    = (const float*)d_in[22];
  const float* b_ff1    = (const float*)d_in[23];
  const float* w_ff2    = (const float*)d_in[24];
  const float* b_ff2    = (const float*)d_in[25];
  const float* w_pout   = (const float*)d_in[26];
  const float* b_pout   = (const float*)d_in[27];
  float* out = (float*)d_out;

  u16* ws = (u16*)d_ws;
  const size_t HB = 4096u*320u;
  u16* h   = ws;
  u16* hn  = ws + HB;
  u16* q   = ws + 2*HB;    // q,k contiguous (QKV fused epilogue)
  u16* k   = ws + 3*HB;
  u16* vT  = ws + 4*HB;    // V^T [320][4096]
  u16* ao  = ws + 5*HB;
  u16* gnT = k;
  u16* gg  = q;            // GEGLU out overlays q,k,vT,ao
  u16* wb  = ws + 6*HB;
  size_t o = 0;
  u16* ctxb   = wb + o; o += 59136;
  u16* wq1T   = wb + o; o += 102400;   // stacked: wq1T,wk1T,wv1T = [960][320]
  u16* wk1T   = wb + o; o += 102400;
  u16* wv1T   = wb + o; o += 102400;
  u16* wo1T   = wb + o; o += 102400;
  u16* wq2T   = wb + o; o += 102400;
  u16* wk2T   = wb + o; o += 245760;   // stacked: wk2T,wv2T = [640][768]
  u16* wv2T   = wb + o; o += 245760;
  u16* wo2T   = wb + o; o += 102400;
  u16* wff1T  = wb + o; o += 819200;
  u16* wff2T  = wb + o; o += 409600;
  u16* wpoutT = wb + o; o += 102400;
  u16* wpinT  = wb + o; o += 102400;
  u16* kc     = wb + o; o += 24640;    // kc,vc contiguous
  u16* vc     = wb + o; o += 24640;
  float* psum = (float*)(wb + o);      // 256 partial sums
  float* psq  = psum + 256;
  u16* OpartB = (u16*)(psq + 256);               // 4 x HB bf16 = 10.5 MB
  float* Lpart = (float*)(OpartB + 4*HB);        // 4 x 32768 fp32

  TPack tp;
  const float* srcs[12] = {wq1, wk1, wv1, wo1, wq2, wo2, w_pin, w_pout, wk2, wv2, w_ff1, w_ff2};
  u16* dsts[12]         = {wq1T, wk1T, wv1T, wo1T, wq2T, wo2T, wpinT, wpoutT, wk2T, wv2T, wff1T, wff2T};
  int Ks[12] = {320,320,320,320,320,320,320,320,768,768,320,1280};
  int Ns[12] = {320,320,320,320,320,320,320,320,320,320,2560,320};
  int off = 0;
  for (int i = 0; i < 12; i++) {
    tp.d[i].src = srcs[i]; tp.d[i].dst = dsts[i];
    tp.d[i].K = Ks[i]; tp.d[i].N = Ns[i];
    tp.d[i].off = off; tp.d[i].tx = Ns[i]/32;
    tp.d[i].sc = (i == 0 || i == 4) ? SCALE_L2E : 1.0f;   // wq1, wq2 pre-scaled
    off += (Ks[i]/32)*(Ns[i]/32);
  }

  dim3 blk(256), g128x10(128, 10);
  const u16* nres = nullptr;
  const float* nb = nullptr;

  // prep: weight tcvt (off) + ctx cvt (58) + gn partial stats (256)
  hipLaunchKernelGGL(prep_kernel, dim3(off + 58 + 256), blk, 0, stream,
                     tp, off, ctx, ctxb, x, psum, psq);
  // fused: gn apply+transpose (320 blocks) || kc/vc GEMM (20 blocks)
  hipLaunchKernelGGL(gn_kcvc, dim3(340), blk, 0, stream,
                     x, psum, psq, gn_s, gn_b, gnT, ctxb, wk2T, kc);
  hipLaunchKernelGGL((oneshot<0>), g128x10, blk, 0, stream, gnT, wpinT, b_pin, nres, nb, (void*)h, 320, 1);
  hipLaunchKernelGGL(layernorm_kernel, dim3(4096), dim3(64), 0, stream, h, ln1_s, ln1_b, hn);
  // fused QKV one-shot: grid (128,30); segs 0,1 -> q,k; seg 2 -> vT
  hipLaunchKernelGGL(qkv_oneshot, dim3(128, 30), blk, 0, stream, hn, wq1T, q, vT, (int)HB);
  hipLaunchKernelGGL(self_attn_part, dim3(32, 8, 4), dim3(512), 0, stream, q, k, vT, OpartB, Lpart);
  hipLaunchKernelGGL(attn_merge, dim3(2560), blk, 0, stream, OpartB, Lpart, ao);
  hipLaunchKernelGGL((oneshot<0>), g128x10, blk, 0, stream, ao, wo1T, bo1, h, nb, (void*)h, 320, 1);
  hipLaunchKernelGGL(layernorm_kernel, dim3(4096), dim3(64), 0, stream, h, ln2_s, ln2_b, hn);
  hipLaunchKernelGGL((oneshot<0>), g128x10, blk, 0, stream, hn, wq2T, nb, nres, nb, (void*)q, 320, 1);
  hipLaunchKernelGGL(cross_attn_mfma, dim3(64, 8), blk, 0, stream, q, kc, vc, ao);
  hipLaunchKernelGGL((oneshot<0>), g128x10, blk, 0, stream, ao, wo2T, bo2, h, nb, (void*)h, 320, 1);
  hipLaunchKernelGGL(layernorm_kernel, dim3(4096), dim3(64), 0, stream, h, ln3_s, ln3_b, hn);
  hipLaunchKernelGGL(geglu_mfma, dim3(128, 20), blk, 0, stream, hn, wff1T, b_ff1, gg);
  hipLaunchKernelGGL((oneshot<0>), g128x10, blk, 0, stream, gg, wff2T, b_ff2, h, nb, (void*)h, 1280, 4);
  hipLaunchKernelGGL((oneshot<2>), g128x10, blk, 0, stream, h, wpoutT, b_pout, nres, x, (void*)out, 320, 1);
}